// Round 1
// baseline (7075.960 us; speedup 1.0000x reference)
//
#include <hip/hip_runtime.h>
#include <hip/hip_bf16.h>
#include <math.h>

#define IN_DIM 256
#define HEADS 8
#define HID 64
#define HC1 512
#define OUT_DIM 40
#define NEG_SLOPE 0.2f

// ---- float <-> order-preserving uint (for atomicMax on floats) ----
__device__ __forceinline__ unsigned f2ord(float f) {
    unsigned u = __float_as_uint(f);
    return (u & 0x80000000u) ? ~u : (u | 0x80000000u);
}
__device__ __forceinline__ float ord2f(unsigned m) {
    unsigned u = (m & 0x80000000u) ? (m & 0x7fffffffu) : ~m;
    return __uint_as_float(u);
}

// ---- GEMM1: h1 = x @ W1, store bf16.  8 nodes per 256-thread block ----
__global__ __launch_bounds__(256) void gemm1_kernel(
    const float* __restrict__ x, const float* __restrict__ W1,
    __hip_bfloat16* __restrict__ h1, int N)
{
    __shared__ float xs[8][IN_DIM];
    const int tid = threadIdx.x;
    const int n0 = blockIdx.x * 8;
#pragma unroll
    for (int i = 0; i < 8; ++i)
        xs[i][tid] = x[(size_t)(n0 + i) * IN_DIM + tid];
    __syncthreads();

    float acc0[8], acc1[8];
#pragma unroll
    for (int i = 0; i < 8; ++i) { acc0[i] = 0.f; acc1[i] = 0.f; }

#pragma unroll 4
    for (int k = 0; k < IN_DIM; ++k) {
        float w0 = W1[(size_t)k * HC1 + tid];
        float w1 = W1[(size_t)k * HC1 + tid + 256];
#pragma unroll
        for (int i = 0; i < 8; ++i) {
            float xv = xs[i][k];
            acc0[i] += xv * w0;
            acc1[i] += xv * w1;
        }
    }
#pragma unroll
    for (int i = 0; i < 8; ++i) {
        h1[(size_t)(n0 + i) * HC1 + tid]       = __float2bfloat16(acc0[i]);
        h1[(size_t)(n0 + i) * HC1 + tid + 256] = __float2bfloat16(acc1[i]);
    }
}

// ---- per-(node,head) attention logits: one wave each ----
__global__ __launch_bounds__(256) void logits1_kernel(
    const __hip_bfloat16* __restrict__ h1, const float* __restrict__ a_src,
    const float* __restrict__ a_dst, float* __restrict__ e_src,
    float* __restrict__ e_dst, int N)
{
    int wid = (blockIdx.x * blockDim.x + threadIdx.x) >> 6;
    int lane = threadIdx.x & 63;
    if (wid >= N * HEADS) return;
    int n = wid >> 3, h = wid & 7;
    float v = __bfloat162float(h1[(size_t)n * HC1 + h * HID + lane]);
    float es = v * a_src[h * HID + lane];
    float ed = v * a_dst[h * HID + lane];
#pragma unroll
    for (int o = 32; o > 0; o >>= 1) {
        es += __shfl_down(es, o);
        ed += __shfl_down(ed, o);
    }
    if (lane == 0) { e_src[wid] = es; e_dst[wid] = ed; }
}

// ---- edge pass 1: segment max (one thread per edge, 8 heads) ----
__global__ __launch_bounds__(256) void edgemax1_kernel(
    const int* __restrict__ ei, const float* __restrict__ e_src,
    const float* __restrict__ e_dst, unsigned* __restrict__ amax, int E, int ET)
{
    int e = blockIdx.x * blockDim.x + threadIdx.x;
    if (e >= ET) return;
    int s, d;
    if (e < E) { s = ei[e]; d = ei[E + e]; } else { s = d = e - E; }
    float as_[8], ad_[8];
    *(float4*)&as_[0] = *(const float4*)(e_src + (size_t)s * 8);
    *(float4*)&as_[4] = *(const float4*)(e_src + (size_t)s * 8 + 4);
    *(float4*)&ad_[0] = *(const float4*)(e_dst + (size_t)d * 8);
    *(float4*)&ad_[4] = *(const float4*)(e_dst + (size_t)d * 8 + 4);
#pragma unroll
    for (int h = 0; h < 8; ++h) {
        float v = as_[h] + ad_[h];
        v = v > 0.f ? v : NEG_SLOPE * v;
        atomicMax(&amax[(size_t)d * 8 + h], f2ord(v));
    }
}

// ---- edge pass 2: ex = exp(alpha - amax), store ex, accumulate denom ----
__global__ __launch_bounds__(256) void edgesum1_kernel(
    const int* __restrict__ ei, const float* __restrict__ e_src,
    const float* __restrict__ e_dst, const unsigned* __restrict__ amax,
    float* __restrict__ ex1, float* __restrict__ denom, int E, int ET)
{
    int e = blockIdx.x * blockDim.x + threadIdx.x;
    if (e >= ET) return;
    int s, d;
    if (e < E) { s = ei[e]; d = ei[E + e]; } else { s = d = e - E; }
    float as_[8], ad_[8];
    *(float4*)&as_[0] = *(const float4*)(e_src + (size_t)s * 8);
    *(float4*)&as_[4] = *(const float4*)(e_src + (size_t)s * 8 + 4);
    *(float4*)&ad_[0] = *(const float4*)(e_dst + (size_t)d * 8);
    *(float4*)&ad_[4] = *(const float4*)(e_dst + (size_t)d * 8 + 4);
#pragma unroll
    for (int h = 0; h < 8; ++h) {
        float v = as_[h] + ad_[h];
        v = v > 0.f ? v : NEG_SLOPE * v;
        float m = ord2f(amax[(size_t)d * 8 + h]);
        float ex = expf(v - m);
        ex1[(size_t)e * 8 + h] = ex;
        atomicAdd(&denom[(size_t)d * 8 + h], ex);
    }
}

// ---- message scatter layer 1: one wave per edge, 512 features ----
__global__ __launch_bounds__(256) void scatter1_kernel(
    const int* __restrict__ ei, const __hip_bfloat16* __restrict__ h1,
    const float* __restrict__ ex1, const float* __restrict__ denom,
    float* __restrict__ out1, int E, int ET)
{
    int wid = (blockIdx.x * blockDim.x + threadIdx.x) >> 6;
    int lane = threadIdx.x & 63;
    if (wid >= ET) return;
    int s, d;
    if (wid < E) { s = ei[wid]; d = ei[E + wid]; } else { s = d = wid - E; }
    int h = lane >> 3;
    float coef = ex1[(size_t)wid * 8 + h] / denom[(size_t)d * 8 + h];
    float4 pv = *(const float4*)(h1 + (size_t)s * HC1 + lane * 8);
    const __hip_bfloat16* hb = (const __hip_bfloat16*)&pv;
    float* o = out1 + (size_t)d * HC1 + lane * 8;
#pragma unroll
    for (int j = 0; j < 8; ++j)
        atomicAdd(o + j, coef * __bfloat162float(hb[j]));
}

// ---- bias + ELU, store bf16 hmid (reuses h1 buffer) ----
__global__ __launch_bounds__(256) void finish1_kernel(
    const float* __restrict__ out1, const float* __restrict__ b1,
    __hip_bfloat16* __restrict__ hmid, int total)
{
    int i = blockIdx.x * 256 + threadIdx.x;
    if (i >= total) return;
    float v = out1[i] + b1[i & (HC1 - 1)];
    v = v > 0.f ? v : expm1f(v);
    hmid[i] = __float2bfloat16(v);
}

// ---- GEMM2 + layer-2 logits: one wave per node ----
__global__ __launch_bounds__(64) void gemm2_kernel(
    const __hip_bfloat16* __restrict__ hmid, const float* __restrict__ W2,
    const float* __restrict__ a_src2, const float* __restrict__ a_dst2,
    float* __restrict__ h2, float* __restrict__ e_src2, float* __restrict__ e_dst2,
    int N)
{
    __shared__ float row[HC1];
    int n = blockIdx.x;
    int lane = threadIdx.x;
    float4 pv = *(const float4*)(hmid + (size_t)n * HC1 + lane * 8);
    const __hip_bfloat16* hb = (const __hip_bfloat16*)&pv;
#pragma unroll
    for (int j = 0; j < 8; ++j)
        row[lane * 8 + j] = __bfloat162float(hb[j]);
    __syncthreads();

    float acc = 0.f;
    if (lane < OUT_DIM) {
#pragma unroll 4
        for (int k = 0; k < HC1; ++k)
            acc += row[k] * W2[(size_t)k * OUT_DIM + lane];
    }
    float es = (lane < OUT_DIM) ? acc * a_src2[lane] : 0.f;
    float ed = (lane < OUT_DIM) ? acc * a_dst2[lane] : 0.f;
#pragma unroll
    for (int o = 32; o > 0; o >>= 1) {
        es += __shfl_down(es, o);
        ed += __shfl_down(ed, o);
    }
    if (lane == 0) { e_src2[n] = es; e_dst2[n] = ed; }
    if (lane < OUT_DIM) h2[(size_t)n * OUT_DIM + lane] = acc;
}

// ---- layer-2 edge passes (H=1) ----
__global__ __launch_bounds__(256) void edgemax2_kernel(
    const int* __restrict__ ei, const float* __restrict__ e_src,
    const float* __restrict__ e_dst, unsigned* __restrict__ amax, int E, int ET)
{
    int e = blockIdx.x * blockDim.x + threadIdx.x;
    if (e >= ET) return;
    int s, d;
    if (e < E) { s = ei[e]; d = ei[E + e]; } else { s = d = e - E; }
    float v = e_src[s] + e_dst[d];
    v = v > 0.f ? v : NEG_SLOPE * v;
    atomicMax(&amax[d], f2ord(v));
}

__global__ __launch_bounds__(256) void edgesum2_kernel(
    const int* __restrict__ ei, const float* __restrict__ e_src,
    const float* __restrict__ e_dst, const unsigned* __restrict__ amax,
    float* __restrict__ ex2, float* __restrict__ denom, int E, int ET)
{
    int e = blockIdx.x * blockDim.x + threadIdx.x;
    if (e >= ET) return;
    int s, d;
    if (e < E) { s = ei[e]; d = ei[E + e]; } else { s = d = e - E; }
    float v = e_src[s] + e_dst[d];
    v = v > 0.f ? v : NEG_SLOPE * v;
    float ex = expf(v - ord2f(amax[d]));
    ex2[e] = ex;
    atomicAdd(&denom[d], ex);
}

// ---- init output with bias b2 ----
__global__ __launch_bounds__(256) void initout_kernel(
    float* __restrict__ out, const float* __restrict__ b2, int total)
{
    int i = blockIdx.x * 256 + threadIdx.x;
    if (i >= total) return;
    int c = i - (i / OUT_DIM) * OUT_DIM;
    out[i] = b2[c];
}

// ---- message scatter layer 2: one wave per edge, 40 features ----
__global__ __launch_bounds__(256) void scatter2_kernel(
    const int* __restrict__ ei, const float* __restrict__ h2,
    const float* __restrict__ ex2, const float* __restrict__ denom,
    float* __restrict__ out, int E, int ET)
{
    int wid = (blockIdx.x * blockDim.x + threadIdx.x) >> 6;
    int lane = threadIdx.x & 63;
    if (wid >= ET) return;
    int s, d;
    if (wid < E) { s = ei[wid]; d = ei[E + wid]; } else { s = d = wid - E; }
    float coef = ex2[wid] / denom[d];
    if (lane < OUT_DIM)
        atomicAdd(out + (size_t)d * OUT_DIM + lane,
                  coef * h2[(size_t)s * OUT_DIM + lane]);
}

extern "C" void kernel_launch(void* const* d_in, const int* in_sizes, int n_in,
                              void* d_out, int out_size, void* d_ws, size_t ws_size,
                              hipStream_t stream)
{
    const float* x      = (const float*)d_in[0];
    const int*   ei     = (const int*)d_in[1];
    const float* W1     = (const float*)d_in[2];
    const float* a_src1 = (const float*)d_in[3];
    const float* a_dst1 = (const float*)d_in[4];
    const float* b1     = (const float*)d_in[5];
    const float* W2     = (const float*)d_in[6];
    const float* a_src2 = (const float*)d_in[7];
    const float* a_dst2 = (const float*)d_in[8];
    const float* b2     = (const float*)d_in[9];
    float* out = (float*)d_out;

    const int N  = in_sizes[0] / IN_DIM;   // 50000
    const int E  = in_sizes[1] / 2;        // 400000
    const int ET = E + N;                  // 450000 (self-loops appended)

    // ---- workspace layout ----
    char* p = (char*)d_ws;
    auto alloc = [&](size_t bytes) -> void* {
        void* r = (void*)p;
        p += (bytes + 255) & ~(size_t)255;
        return r;
    };
    __hip_bfloat16* h1b   = (__hip_bfloat16*)alloc((size_t)N * HC1 * 2); // also hmid later
    float*    out1   = (float*)alloc((size_t)N * HC1 * 4);               // also h2 later
    float*    e_src1 = (float*)alloc((size_t)N * HEADS * 4);
    float*    e_dst1 = (float*)alloc((size_t)N * HEADS * 4);
    unsigned* amax1  = (unsigned*)alloc((size_t)N * HEADS * 4);
    float*    denom1 = (float*)alloc((size_t)N * HEADS * 4);
    float*    ex1    = (float*)alloc((size_t)ET * HEADS * 4);
    float*    e_src2 = (float*)alloc((size_t)N * 4);
    float*    e_dst2 = (float*)alloc((size_t)N * 4);
    unsigned* amax2  = (unsigned*)alloc((size_t)N * 4);
    float*    denom2 = (float*)alloc((size_t)N * 4);
    float*    ex2    = (float*)alloc((size_t)ET * 4);
    float*    h2     = out1;  // reuse after finish1 consumed out1

    // ---- zero-init accumulators (every call; harness poisons ws) ----
    hipMemsetAsync(out1,   0, (size_t)N * HC1 * 4, stream);
    hipMemsetAsync(amax1,  0, (size_t)N * HEADS * 4, stream);
    hipMemsetAsync(denom1, 0, (size_t)N * HEADS * 4, stream);
    hipMemsetAsync(amax2,  0, (size_t)N * 4, stream);
    hipMemsetAsync(denom2, 0, (size_t)N * 4, stream);

    // ---- layer 1 ----
    gemm1_kernel<<<N / 8, 256, 0, stream>>>(x, W1, h1b, N);
    {
        int waves = N * HEADS;
        logits1_kernel<<<(waves + 3) / 4, 256, 0, stream>>>(h1b, a_src1, a_dst1,
                                                            e_src1, e_dst1, N);
    }
    {
        int blocks = (ET + 255) / 256;
        edgemax1_kernel<<<blocks, 256, 0, stream>>>(ei, e_src1, e_dst1, amax1, E, ET);
        edgesum1_kernel<<<blocks, 256, 0, stream>>>(ei, e_src1, e_dst1, amax1,
                                                    ex1, denom1, E, ET);
    }
    {
        int blocks = (ET + 3) / 4;  // 4 waves per block
        scatter1_kernel<<<blocks, 256, 0, stream>>>(ei, h1b, ex1, denom1, out1, E, ET);
    }
    {
        int total = N * HC1;
        finish1_kernel<<<(total + 255) / 256, 256, 0, stream>>>(out1, b1, h1b, total);
    }

    // ---- layer 2 ----
    gemm2_kernel<<<N, 64, 0, stream>>>(h1b, W2, a_src2, a_dst2, h2, e_src2, e_dst2, N);
    {
        int blocks = (ET + 255) / 256;
        edgemax2_kernel<<<blocks, 256, 0, stream>>>(ei, e_src2, e_dst2, amax2, E, ET);
        edgesum2_kernel<<<blocks, 256, 0, stream>>>(ei, e_src2, e_dst2, amax2,
                                                    ex2, denom2, E, ET);
    }
    {
        int total = N * OUT_DIM;
        initout_kernel<<<(total + 255) / 256, 256, 0, stream>>>(out, b2, total);
    }
    {
        int blocks = (ET + 3) / 4;
        scatter2_kernel<<<blocks, 256, 0, stream>>>(ei, h2, ex2, denom2, out, E, ET);
    }
}

// Round 2
// 719.981 us; speedup vs baseline: 9.8280x; 9.8280x over previous
//
#include <hip/hip_runtime.h>
#include <hip/hip_bf16.h>
#include <math.h>

#define IN_DIM 256
#define HEADS 8
#define HID 64
#define HC1 512
#define OUT_DIM 40
#define NEG_SLOPE 0.2f

// ================= CSR build (dst-sorted edge list) =================

__global__ __launch_bounds__(256) void degree_kernel(
    const int* __restrict__ ei, int* __restrict__ deg, int E, int ET)
{
    int e = blockIdx.x * 256 + threadIdx.x;
    if (e >= ET) return;
    int d = (e < E) ? ei[E + e] : e - E;
    atomicAdd(&deg[d], 1);
}

__global__ __launch_bounds__(256) void scan1_kernel(
    const int* __restrict__ deg, int* __restrict__ rowptr,
    int* __restrict__ aux, int N)
{
    __shared__ int sd[256];
    int tid = threadIdx.x;
    int i = blockIdx.x * 256 + tid;
    int v = (i < N) ? deg[i] : 0;
    sd[tid] = v;
    __syncthreads();
    for (int off = 1; off < 256; off <<= 1) {
        int t = (tid >= off) ? sd[tid - off] : 0;
        __syncthreads();
        sd[tid] += t;
        __syncthreads();
    }
    if (i < N) rowptr[i] = sd[tid] - v;          // exclusive within block
    if (tid == 255) aux[blockIdx.x] = sd[255];   // block total
}

__global__ __launch_bounds__(256) void scan_aux_kernel(int* __restrict__ aux, int nb)
{
    __shared__ int sd[256];
    int tid = threadIdx.x;
    int v = (tid < nb) ? aux[tid] : 0;
    sd[tid] = v;
    __syncthreads();
    for (int off = 1; off < 256; off <<= 1) {
        int t = (tid >= off) ? sd[tid - off] : 0;
        __syncthreads();
        sd[tid] += t;
        __syncthreads();
    }
    if (tid < nb) aux[tid] = sd[tid] - v;        // exclusive
}

__global__ __launch_bounds__(256) void scan_add_kernel(
    int* __restrict__ rowptr, const int* __restrict__ aux, int N, int ET)
{
    int i = blockIdx.x * 256 + threadIdx.x;
    if (i < N) rowptr[i] += aux[blockIdx.x];
    if (i == 0) rowptr[N] = ET;
}

__global__ __launch_bounds__(256) void build_kernel(
    const int* __restrict__ ei, int* __restrict__ cursor,
    int* __restrict__ csr_src, int E, int ET)
{
    int e = blockIdx.x * 256 + threadIdx.x;
    if (e >= ET) return;
    int s, d;
    if (e < E) { s = ei[e]; d = ei[E + e]; } else { s = d = e - E; }
    int pos = atomicAdd(&cursor[d], 1);
    csr_src[pos] = s;
}

// ================= layer 1 =================

// h1 = x @ W1 (bf16 out). 8 nodes per 256-thread block.
__global__ __launch_bounds__(256) void gemm1_kernel(
    const float* __restrict__ x, const float* __restrict__ W1,
    __hip_bfloat16* __restrict__ h1, int N)
{
    __shared__ float xs[8][IN_DIM];
    const int tid = threadIdx.x;
    const int n0 = blockIdx.x * 8;
#pragma unroll
    for (int i = 0; i < 8; ++i)
        xs[i][tid] = x[(size_t)(n0 + i) * IN_DIM + tid];
    __syncthreads();

    float acc0[8], acc1[8];
#pragma unroll
    for (int i = 0; i < 8; ++i) { acc0[i] = 0.f; acc1[i] = 0.f; }

#pragma unroll 4
    for (int k = 0; k < IN_DIM; ++k) {
        float w0 = W1[(size_t)k * HC1 + tid];
        float w1 = W1[(size_t)k * HC1 + tid + 256];
#pragma unroll
        for (int i = 0; i < 8; ++i) {
            float xv = xs[i][k];
            acc0[i] += xv * w0;
            acc1[i] += xv * w1;
        }
    }
#pragma unroll
    for (int i = 0; i < 8; ++i) {
        h1[(size_t)(n0 + i) * HC1 + tid]       = __float2bfloat16(acc0[i]);
        h1[(size_t)(n0 + i) * HC1 + tid + 256] = __float2bfloat16(acc1[i]);
    }
}

// per-(node,head) logits: one wave each
__global__ __launch_bounds__(256) void logits1_kernel(
    const __hip_bfloat16* __restrict__ h1, const float* __restrict__ a_src,
    const float* __restrict__ a_dst, float* __restrict__ e_src,
    float* __restrict__ e_dst, int N)
{
    int wid = (blockIdx.x * blockDim.x + threadIdx.x) >> 6;
    int lane = threadIdx.x & 63;
    if (wid >= N * HEADS) return;
    int n = wid >> 3, h = wid & 7;
    float v = __bfloat162float(h1[(size_t)n * HC1 + h * HID + lane]);
    float es = v * a_src[h * HID + lane];
    float ed = v * a_dst[h * HID + lane];
#pragma unroll
    for (int o = 32; o > 0; o >>= 1) {
        es += __shfl_down(es, o);
        ed += __shfl_down(ed, o);
    }
    if (lane == 0) { e_src[wid] = es; e_dst[wid] = ed; }
}

// per-node softmax over incoming edges (CSR). 1 wave/node.
// lane = (edge-in-chunk i = lane>>3, head h = lane&7). Stores ex in coef,
// 1/sum in invden (normalization folded into gather epilogue).
__global__ __launch_bounds__(256) void softmax1_kernel(
    const int* __restrict__ rowptr, const int* __restrict__ csr_src,
    const float* __restrict__ e_src, const float* __restrict__ e_dst,
    float* __restrict__ coef, float* __restrict__ invden, int N)
{
    int wid = (blockIdx.x * blockDim.x + threadIdx.x) >> 6;
    if (wid >= N) return;
    int lane = threadIdx.x & 63;
    int i = lane >> 3, h = lane & 7;
    int base = rowptr[wid];
    int deg = rowptr[wid + 1] - base;
    float edv = e_dst[wid * 8 + h];
    int nc = (deg + 7) >> 3;

    float m = -INFINITY;
    for (int c = 0; c < nc; ++c) {
        int k = c * 8 + i;
        float a = -INFINITY;
        if (k < deg) {
            int s = csr_src[base + k];
            a = e_src[(size_t)s * 8 + h] + edv;
            a = a > 0.f ? a : NEG_SLOPE * a;
        }
        m = fmaxf(m, a);
    }
    m = fmaxf(m, __shfl_xor(m, 8));
    m = fmaxf(m, __shfl_xor(m, 16));
    m = fmaxf(m, __shfl_xor(m, 32));

    float ssum = 0.f;
    for (int c = 0; c < nc; ++c) {
        int k = c * 8 + i;
        if (k < deg) {
            int s = csr_src[base + k];
            float a = e_src[(size_t)s * 8 + h] + edv;
            a = a > 0.f ? a : NEG_SLOPE * a;
            float ex = expf(a - m);
            coef[(size_t)(base + k) * 8 + h] = ex;
            ssum += ex;
        }
    }
    ssum += __shfl_xor(ssum, 8);
    ssum += __shfl_xor(ssum, 16);
    ssum += __shfl_xor(ssum, 32);
    if (lane < 8) invden[wid * 8 + lane] = 1.f / ssum;
}

// gather + normalize + bias + ELU + bf16 cast. One block per dst node,
// thread t owns features (2t, 2t+1), head h0 = t>>5.
__global__ __launch_bounds__(256) void gather1_kernel(
    const int* __restrict__ rowptr, const int* __restrict__ csr_src,
    const __hip_bfloat16* __restrict__ h1, const float* __restrict__ coef,
    const float* __restrict__ invden, const float* __restrict__ b1,
    __hip_bfloat16* __restrict__ hmid, int N)
{
    int d = blockIdx.x;
    int t = threadIdx.x;
    int h0 = t >> 5;
    int base = rowptr[d], end = rowptr[d + 1];
    float acc0 = 0.f, acc1 = 0.f;
    for (int j = base; j < end; ++j) {
        int s = csr_src[j];
        float c = coef[(size_t)j * 8 + h0];
        unsigned uv = *(const unsigned*)(h1 + (size_t)s * HC1 + 2 * t);
        const __hip_bfloat16* hb = (const __hip_bfloat16*)&uv;
        acc0 += c * __bfloat162float(hb[0]);
        acc1 += c * __bfloat162float(hb[1]);
    }
    float inv = invden[d * 8 + h0];
    float o0 = acc0 * inv + b1[2 * t];
    float o1 = acc1 * inv + b1[2 * t + 1];
    o0 = o0 > 0.f ? o0 : expm1f(o0);
    o1 = o1 > 0.f ? o1 : expm1f(o1);
    __hip_bfloat16 r[2] = { __float2bfloat16(o0), __float2bfloat16(o1) };
    *(unsigned*)(hmid + (size_t)d * HC1 + 2 * t) = *(unsigned*)r;
}

// ================= layer 2 =================

// h2 = hmid @ W2 + layer-2 logits. One wave per node.
__global__ __launch_bounds__(64) void gemm2_kernel(
    const __hip_bfloat16* __restrict__ hmid, const float* __restrict__ W2,
    const float* __restrict__ a_src2, const float* __restrict__ a_dst2,
    float* __restrict__ h2, float* __restrict__ e_src2, float* __restrict__ e_dst2,
    int N)
{
    __shared__ float row[HC1];
    int n = blockIdx.x;
    int lane = threadIdx.x;
    float4 pv = *(const float4*)(hmid + (size_t)n * HC1 + lane * 8);
    const __hip_bfloat16* hb = (const __hip_bfloat16*)&pv;
#pragma unroll
    for (int j = 0; j < 8; ++j)
        row[lane * 8 + j] = __bfloat162float(hb[j]);
    __syncthreads();

    float acc = 0.f;
    if (lane < OUT_DIM) {
#pragma unroll 4
        for (int k = 0; k < HC1; ++k)
            acc += row[k] * W2[(size_t)k * OUT_DIM + lane];
    }
    float es = (lane < OUT_DIM) ? acc * a_src2[lane] : 0.f;
    float ed = (lane < OUT_DIM) ? acc * a_dst2[lane] : 0.f;
#pragma unroll
    for (int o = 32; o > 0; o >>= 1) {
        es += __shfl_down(es, o);
        ed += __shfl_down(ed, o);
    }
    if (lane == 0) { e_src2[n] = es; e_dst2[n] = ed; }
    if (lane < OUT_DIM) h2[(size_t)n * OUT_DIM + lane] = acc;
}

// per-node softmax (H=1), CSR. 1 wave/node, lane = edge offset in chunk of 64.
__global__ __launch_bounds__(256) void softmax2_kernel(
    const int* __restrict__ rowptr, const int* __restrict__ csr_src,
    const float* __restrict__ e_src, const float* __restrict__ e_dst,
    float* __restrict__ coef2, float* __restrict__ invden2, int N)
{
    int wid = (blockIdx.x * blockDim.x + threadIdx.x) >> 6;
    if (wid >= N) return;
    int lane = threadIdx.x & 63;
    int base = rowptr[wid];
    int deg = rowptr[wid + 1] - base;
    float edv = e_dst[wid];
    int nc = (deg + 63) >> 6;

    float m = -INFINITY;
    for (int c = 0; c < nc; ++c) {
        int k = c * 64 + lane;
        float a = -INFINITY;
        if (k < deg) {
            int s = csr_src[base + k];
            a = e_src[s] + edv;
            a = a > 0.f ? a : NEG_SLOPE * a;
        }
        m = fmaxf(m, a);
    }
#pragma unroll
    for (int o = 1; o < 64; o <<= 1) m = fmaxf(m, __shfl_xor(m, o));

    float ssum = 0.f;
    for (int c = 0; c < nc; ++c) {
        int k = c * 64 + lane;
        if (k < deg) {
            int s = csr_src[base + k];
            float a = e_src[s] + edv;
            a = a > 0.f ? a : NEG_SLOPE * a;
            float ex = expf(a - m);
            coef2[base + k] = ex;
            ssum += ex;
        }
    }
#pragma unroll
    for (int o = 1; o < 64; o <<= 1) ssum += __shfl_xor(ssum, o);
    if (lane == 0) invden2[wid] = 1.f / ssum;
}

// gather layer 2 + bias. One wave per dst node, lane<40 = feature.
__global__ __launch_bounds__(256) void gather2_kernel(
    const int* __restrict__ rowptr, const int* __restrict__ csr_src,
    const float* __restrict__ h2, const float* __restrict__ coef2,
    const float* __restrict__ invden2, const float* __restrict__ b2,
    float* __restrict__ out, int N)
{
    int wid = (blockIdx.x * blockDim.x + threadIdx.x) >> 6;
    if (wid >= N) return;
    int lane = threadIdx.x & 63;
    int base = rowptr[wid], end = rowptr[wid + 1];
    float acc = 0.f;
    for (int j = base; j < end; ++j) {
        int s = csr_src[j];
        float c = coef2[j];
        if (lane < OUT_DIM) acc += c * h2[(size_t)s * OUT_DIM + lane];
    }
    if (lane < OUT_DIM)
        out[(size_t)wid * OUT_DIM + lane] = acc * invden2[wid] + b2[lane];
}

extern "C" void kernel_launch(void* const* d_in, const int* in_sizes, int n_in,
                              void* d_out, int out_size, void* d_ws, size_t ws_size,
                              hipStream_t stream)
{
    const float* x      = (const float*)d_in[0];
    const int*   ei     = (const int*)d_in[1];
    const float* W1     = (const float*)d_in[2];
    const float* a_src1 = (const float*)d_in[3];
    const float* a_dst1 = (const float*)d_in[4];
    const float* b1     = (const float*)d_in[5];
    const float* W2     = (const float*)d_in[6];
    const float* a_src2 = (const float*)d_in[7];
    const float* a_dst2 = (const float*)d_in[8];
    const float* b2     = (const float*)d_in[9];
    float* out = (float*)d_out;

    const int N  = in_sizes[0] / IN_DIM;   // 50000
    const int E  = in_sizes[1] / 2;        // 400000
    const int ET = E + N;                  // 450000

    // ---- workspace layout ----
    char* p = (char*)d_ws;
    auto alloc = [&](size_t bytes) -> void* {
        void* r = (void*)p;
        p += (bytes + 255) & ~(size_t)255;
        return r;
    };
    __hip_bfloat16* h1b    = (__hip_bfloat16*)alloc((size_t)N * HC1 * 2);
    __hip_bfloat16* hmid   = (__hip_bfloat16*)alloc((size_t)N * HC1 * 2);
    float*    h2      = (float*)alloc((size_t)N * OUT_DIM * 4);
    float*    e_src1  = (float*)alloc((size_t)N * HEADS * 4);
    float*    e_dst1  = (float*)alloc((size_t)N * HEADS * 4);
    float*    invden1 = (float*)alloc((size_t)N * HEADS * 4);
    float*    coef1   = (float*)alloc((size_t)ET * HEADS * 4);
    float*    e_src2  = (float*)alloc((size_t)N * 4);
    float*    e_dst2  = (float*)alloc((size_t)N * 4);
    float*    invden2 = (float*)alloc((size_t)N * 4);
    float*    coef2   = (float*)alloc((size_t)ET * 4);
    int*      deg     = (int*)alloc((size_t)N * 4);
    int*      rowptr  = (int*)alloc((size_t)(N + 1) * 4);
    int*      cursor  = (int*)alloc((size_t)N * 4);
    int*      csr_src = (int*)alloc((size_t)ET * 4);
    int*      aux     = (int*)alloc(256 * 4);

    const int nbN  = (N + 255) / 256;   // scan blocks (196 <= 256)
    const int nbET = (ET + 255) / 256;

    // ---- CSR build ----
    hipMemsetAsync(deg, 0, (size_t)N * 4, stream);
    degree_kernel<<<nbET, 256, 0, stream>>>(ei, deg, E, ET);
    scan1_kernel<<<nbN, 256, 0, stream>>>(deg, rowptr, aux, N);
    scan_aux_kernel<<<1, 256, 0, stream>>>(aux, nbN);
    scan_add_kernel<<<nbN, 256, 0, stream>>>(rowptr, aux, N, ET);
    hipMemcpyAsync(cursor, rowptr, (size_t)N * 4, hipMemcpyDeviceToDevice, stream);
    build_kernel<<<nbET, 256, 0, stream>>>(ei, cursor, csr_src, E, ET);

    // ---- layer 1 ----
    gemm1_kernel<<<N / 8, 256, 0, stream>>>(x, W1, h1b, N);
    logits1_kernel<<<(N * HEADS + 3) / 4, 256, 0, stream>>>(h1b, a_src1, a_dst1,
                                                            e_src1, e_dst1, N);
    softmax1_kernel<<<(N + 3) / 4, 256, 0, stream>>>(rowptr, csr_src, e_src1,
                                                     e_dst1, coef1, invden1, N);
    gather1_kernel<<<N, 256, 0, stream>>>(rowptr, csr_src, h1b, coef1, invden1,
                                          b1, hmid, N);

    // ---- layer 2 ----
    gemm2_kernel<<<N, 64, 0, stream>>>(hmid, W2, a_src2, a_dst2, h2,
                                       e_src2, e_dst2, N);
    softmax2_kernel<<<(N + 3) / 4, 256, 0, stream>>>(rowptr, csr_src, e_src2,
                                                     e_dst2, coef2, invden2, N);
    gather2_kernel<<<(N + 3) / 4, 256, 0, stream>>>(rowptr, csr_src, h2, coef2,
                                                    invden2, b2, out, N);
}

// Round 3
// 424.294 us; speedup vs baseline: 16.6770x; 1.6969x over previous
//
#include <hip/hip_runtime.h>
#include <hip/hip_bf16.h>
#include <math.h>

#define IN_DIM 256
#define HEADS 8
#define HID 64
#define HC1 512
#define OUT_DIM 40
#define NEG_SLOPE 0.2f

typedef __attribute__((ext_vector_type(8))) short short8;
typedef __attribute__((ext_vector_type(4))) float f32x4;

__device__ __forceinline__ unsigned short f2b(float f) {
    __hip_bfloat16 h = __float2bfloat16(f);
    unsigned short u;
    __builtin_memcpy(&u, &h, 2);
    return u;
}

// ================= weight prep =================

// W1 [256][512] f32 -> W1T [512][256] bf16
__global__ __launch_bounds__(256) void prep_w1t(
    const float* __restrict__ W1, __hip_bfloat16* __restrict__ W1T)
{
    int i = blockIdx.x * 256 + threadIdx.x;
    if (i >= HC1 * IN_DIM) return;
    int n = i >> 8, k = i & 255;
    W1T[i] = __float2bfloat16(W1[(size_t)k * HC1 + n]);
}

// W2 [512][40] f32 -> W2T [48][512] bf16 (zero-padded cols 40..47)
__global__ __launch_bounds__(256) void prep_w2t(
    const float* __restrict__ W2, __hip_bfloat16* __restrict__ W2T)
{
    int i = blockIdx.x * 256 + threadIdx.x;
    if (i >= 48 * HC1) return;
    int n = i >> 9, k = i & 511;
    W2T[i] = __float2bfloat16(n < OUT_DIM ? W2[(size_t)k * OUT_DIM + n] : 0.f);
}

// ================= CSR build =================

__global__ __launch_bounds__(256) void degree_kernel(
    const int* __restrict__ ei, int* __restrict__ deg, int E, int ET)
{
    int e = blockIdx.x * 256 + threadIdx.x;
    if (e >= ET) return;
    int d = (e < E) ? ei[E + e] : e - E;
    atomicAdd(&deg[d], 1);
}

__global__ __launch_bounds__(256) void scan1_kernel(
    const int* __restrict__ deg, int* __restrict__ rowptr,
    int* __restrict__ aux, int N)
{
    __shared__ int sd[256];
    int tid = threadIdx.x;
    int i = blockIdx.x * 256 + tid;
    int v = (i < N) ? deg[i] : 0;
    sd[tid] = v;
    __syncthreads();
    for (int off = 1; off < 256; off <<= 1) {
        int t = (tid >= off) ? sd[tid - off] : 0;
        __syncthreads();
        sd[tid] += t;
        __syncthreads();
    }
    if (i < N) rowptr[i] = sd[tid] - v;
    if (tid == 255) aux[blockIdx.x] = sd[255];
}

__global__ __launch_bounds__(256) void scan_aux_kernel(int* __restrict__ aux, int nb)
{
    __shared__ int sd[256];
    int tid = threadIdx.x;
    int v = (tid < nb) ? aux[tid] : 0;
    sd[tid] = v;
    __syncthreads();
    for (int off = 1; off < 256; off <<= 1) {
        int t = (tid >= off) ? sd[tid - off] : 0;
        __syncthreads();
        sd[tid] += t;
        __syncthreads();
    }
    if (tid < nb) aux[tid] = sd[tid] - v;
}

__global__ __launch_bounds__(256) void scan_add_kernel(
    int* __restrict__ rowptr, const int* __restrict__ aux, int N, int ET)
{
    int i = blockIdx.x * 256 + threadIdx.x;
    if (i < N) rowptr[i] += aux[blockIdx.x];
    if (i == 0) rowptr[N] = ET;
}

__global__ __launch_bounds__(256) void build_kernel(
    const int* __restrict__ ei, int* __restrict__ cursor,
    int* __restrict__ csr_src, int E, int ET)
{
    int e = blockIdx.x * 256 + threadIdx.x;
    if (e >= ET) return;
    int s, d;
    if (e < E) { s = ei[e]; d = ei[E + e]; } else { s = d = e - E; }
    int pos = atomicAdd(&cursor[d], 1);
    csr_src[pos] = s;
}

// ================= layer 1: MFMA GEMM + fused logits =================
// Block: 4 waves, 16 rows x 512 cols. Wave w: cols [w*128, w*128+128) = heads 2w, 2w+1.
// Grid: N/16 = 3125 blocks (exact).
__global__ __launch_bounds__(256) void gemm1_mfma(
    const float* __restrict__ x, const __hip_bfloat16* __restrict__ W1T,
    const float* __restrict__ a_src1, const float* __restrict__ a_dst1,
    __hip_bfloat16* __restrict__ h1, float* __restrict__ e_src1,
    float* __restrict__ e_dst1, int N)
{
    const int w = threadIdx.x >> 6;
    const int lane = threadIdx.x & 63;
    const int r = lane & 15, g = lane >> 4;
    const int row0 = blockIdx.x * 16;
    const int col0 = w * 128;

    f32x4 acc[8] = {};
    const float* xp = x + (size_t)(row0 + r) * IN_DIM + 8 * g;
    const short* bp = (const short*)W1T;

    for (int kk = 0; kk < IN_DIM; kk += 32) {
        float4 a0 = *(const float4*)(xp + kk);
        float4 a1 = *(const float4*)(xp + kk + 4);
        short8 af;
        af[0] = f2b(a0.x); af[1] = f2b(a0.y); af[2] = f2b(a0.z); af[3] = f2b(a0.w);
        af[4] = f2b(a1.x); af[5] = f2b(a1.y); af[6] = f2b(a1.z); af[7] = f2b(a1.w);
#pragma unroll
        for (int t = 0; t < 8; ++t) {
            int n = col0 + t * 16 + r;
            short8 bf = *(const short8*)(bp + (size_t)n * IN_DIM + kk + 8 * g);
            acc[t] = __builtin_amdgcn_mfma_f32_16x16x32_bf16(af, bf, acc[t], 0, 0, 0);
        }
    }

    // store h1 (D layout: col = lane&15 within tile, row = 4*g + q)
#pragma unroll
    for (int t = 0; t < 8; ++t) {
        int c = col0 + t * 16 + r;
#pragma unroll
        for (int q = 0; q < 4; ++q)
            h1[(size_t)(row0 + 4 * g + q) * HC1 + c] = __float2bfloat16(acc[t][q]);
    }

    // fused per-head logits: head A = 2w (tiles 0..3), head B = 2w+1 (tiles 4..7)
    float psa[4] = {0,0,0,0}, pda[4] = {0,0,0,0};
    float psb[4] = {0,0,0,0}, pdb[4] = {0,0,0,0};
#pragma unroll
    for (int t = 0; t < 8; ++t) {
        int hh = 2 * w + (t >> 2);
        int cc = hh * HID + (t & 3) * 16 + r;
        float a1v = a_src1[cc];
        float a2v = a_dst1[cc];
        if (t < 4) {
#pragma unroll
            for (int q = 0; q < 4; ++q) { psa[q] += acc[t][q] * a1v; pda[q] += acc[t][q] * a2v; }
        } else {
#pragma unroll
            for (int q = 0; q < 4; ++q) { psb[q] += acc[t][q] * a1v; pdb[q] += acc[t][q] * a2v; }
        }
    }
#pragma unroll
    for (int off = 1; off < 16; off <<= 1) {
#pragma unroll
        for (int q = 0; q < 4; ++q) {
            psa[q] += __shfl_xor(psa[q], off);
            pda[q] += __shfl_xor(pda[q], off);
            psb[q] += __shfl_xor(psb[q], off);
            pdb[q] += __shfl_xor(pdb[q], off);
        }
    }
    if (r == 0) {
#pragma unroll
        for (int q = 0; q < 4; ++q) {
            int row = row0 + 4 * g + q;
            e_src1[row * 8 + 2 * w]     = psa[q];
            e_dst1[row * 8 + 2 * w]     = pda[q];
            e_src1[row * 8 + 2 * w + 1] = psb[q];
            e_dst1[row * 8 + 2 * w + 1] = pdb[q];
        }
    }
}

// ================= softmax / gather layer 1 (unchanged) =================

__global__ __launch_bounds__(256) void softmax1_kernel(
    const int* __restrict__ rowptr, const int* __restrict__ csr_src,
    const float* __restrict__ e_src, const float* __restrict__ e_dst,
    float* __restrict__ coef, float* __restrict__ invden, int N)
{
    int wid = (blockIdx.x * blockDim.x + threadIdx.x) >> 6;
    if (wid >= N) return;
    int lane = threadIdx.x & 63;
    int i = lane >> 3, h = lane & 7;
    int base = rowptr[wid];
    int deg = rowptr[wid + 1] - base;
    float edv = e_dst[wid * 8 + h];
    int nc = (deg + 7) >> 3;

    float m = -INFINITY;
    for (int c = 0; c < nc; ++c) {
        int k = c * 8 + i;
        float a = -INFINITY;
        if (k < deg) {
            int s = csr_src[base + k];
            a = e_src[(size_t)s * 8 + h] + edv;
            a = a > 0.f ? a : NEG_SLOPE * a;
        }
        m = fmaxf(m, a);
    }
    m = fmaxf(m, __shfl_xor(m, 8));
    m = fmaxf(m, __shfl_xor(m, 16));
    m = fmaxf(m, __shfl_xor(m, 32));

    float ssum = 0.f;
    for (int c = 0; c < nc; ++c) {
        int k = c * 8 + i;
        if (k < deg) {
            int s = csr_src[base + k];
            float a = e_src[(size_t)s * 8 + h] + edv;
            a = a > 0.f ? a : NEG_SLOPE * a;
            float ex = expf(a - m);
            coef[(size_t)(base + k) * 8 + h] = ex;
            ssum += ex;
        }
    }
    ssum += __shfl_xor(ssum, 8);
    ssum += __shfl_xor(ssum, 16);
    ssum += __shfl_xor(ssum, 32);
    if (lane < 8) invden[wid * 8 + lane] = 1.f / ssum;
}

__global__ __launch_bounds__(256) void gather1_kernel(
    const int* __restrict__ rowptr, const int* __restrict__ csr_src,
    const __hip_bfloat16* __restrict__ h1, const float* __restrict__ coef,
    const float* __restrict__ invden, const float* __restrict__ b1,
    __hip_bfloat16* __restrict__ hmid, int N)
{
    int d = blockIdx.x;
    int t = threadIdx.x;
    int h0 = t >> 5;
    int base = rowptr[d], end = rowptr[d + 1];
    float acc0 = 0.f, acc1 = 0.f;
    for (int j = base; j < end; ++j) {
        int s = csr_src[j];
        float c = coef[(size_t)j * 8 + h0];
        unsigned uv = *(const unsigned*)(h1 + (size_t)s * HC1 + 2 * t);
        const __hip_bfloat16* hb = (const __hip_bfloat16*)&uv;
        acc0 += c * __bfloat162float(hb[0]);
        acc1 += c * __bfloat162float(hb[1]);
    }
    float inv = invden[d * 8 + h0];
    float o0 = acc0 * inv + b1[2 * t];
    float o1 = acc1 * inv + b1[2 * t + 1];
    o0 = o0 > 0.f ? o0 : expm1f(o0);
    o1 = o1 > 0.f ? o1 : expm1f(o1);
    __hip_bfloat16 rr[2] = { __float2bfloat16(o0), __float2bfloat16(o1) };
    *(unsigned*)(hmid + (size_t)d * HC1 + 2 * t) = *(unsigned*)rr;
}

// ================= layer 2: MFMA GEMM + fused logits =================
// Block: 4 waves, 64 rows; wave w: rows [b*64+w*16, +16), 48 cols (3 n-tiles).
__global__ __launch_bounds__(256) void gemm2_mfma(
    const __hip_bfloat16* __restrict__ hmid, const __hip_bfloat16* __restrict__ W2T,
    const float* __restrict__ a_src2, const float* __restrict__ a_dst2,
    float* __restrict__ h2, float* __restrict__ e_src2, float* __restrict__ e_dst2,
    int N)
{
    const int w = threadIdx.x >> 6;
    const int lane = threadIdx.x & 63;
    const int r = lane & 15, g = lane >> 4;
    const int rowW = blockIdx.x * 64 + w * 16;
    int arow = rowW + r;
    if (arow >= N) arow = N - 1;  // clamped read; writes guarded

    f32x4 acc[3] = {};
    const short* ap = (const short*)hmid + (size_t)arow * HC1 + 8 * g;
    const short* bp = (const short*)W2T + 8 * g;

    for (int kk = 0; kk < HC1; kk += 32) {
        short8 af = *(const short8*)(ap + kk);
#pragma unroll
        for (int t = 0; t < 3; ++t) {
            short8 bf = *(const short8*)(bp + (size_t)(t * 16 + r) * HC1 + kk);
            acc[t] = __builtin_amdgcn_mfma_f32_16x16x32_bf16(af, bf, acc[t], 0, 0, 0);
        }
    }

    // h2 store
#pragma unroll
    for (int t = 0; t < 3; ++t) {
        int c = 16 * t + r;
        if (c < OUT_DIM) {
#pragma unroll
            for (int q = 0; q < 4; ++q) {
                int row = rowW + 4 * g + q;
                if (row < N) h2[(size_t)row * OUT_DIM + c] = acc[t][q];
            }
        }
    }

    // fused logits2
    float as[3], ad[3];
#pragma unroll
    for (int t = 0; t < 3; ++t) {
        int c = 16 * t + r;
        as[t] = (c < OUT_DIM) ? a_src2[c] : 0.f;
        ad[t] = (c < OUT_DIM) ? a_dst2[c] : 0.f;
    }
    float ps[4] = {0,0,0,0}, pd[4] = {0,0,0,0};
#pragma unroll
    for (int t = 0; t < 3; ++t)
#pragma unroll
        for (int q = 0; q < 4; ++q) { ps[q] += acc[t][q] * as[t]; pd[q] += acc[t][q] * ad[t]; }
#pragma unroll
    for (int off = 1; off < 16; off <<= 1) {
#pragma unroll
        for (int q = 0; q < 4; ++q) {
            ps[q] += __shfl_xor(ps[q], off);
            pd[q] += __shfl_xor(pd[q], off);
        }
    }
    if (r == 0) {
#pragma unroll
        for (int q = 0; q < 4; ++q) {
            int row = rowW + 4 * g + q;
            if (row < N) { e_src2[row] = ps[q]; e_dst2[row] = pd[q]; }
        }
    }
}

// ================= softmax / gather layer 2 (unchanged) =================

__global__ __launch_bounds__(256) void softmax2_kernel(
    const int* __restrict__ rowptr, const int* __restrict__ csr_src,
    const float* __restrict__ e_src, const float* __restrict__ e_dst,
    float* __restrict__ coef2, float* __restrict__ invden2, int N)
{
    int wid = (blockIdx.x * blockDim.x + threadIdx.x) >> 6;
    if (wid >= N) return;
    int lane = threadIdx.x & 63;
    int base = rowptr[wid];
    int deg = rowptr[wid + 1] - base;
    float edv = e_dst[wid];
    int nc = (deg + 63) >> 6;

    float m = -INFINITY;
    for (int c = 0; c < nc; ++c) {
        int k = c * 64 + lane;
        float a = -INFINITY;
        if (k < deg) {
            int s = csr_src[base + k];
            a = e_src[s] + edv;
            a = a > 0.f ? a : NEG_SLOPE * a;
        }
        m = fmaxf(m, a);
    }
#pragma unroll
    for (int o = 1; o < 64; o <<= 1) m = fmaxf(m, __shfl_xor(m, o));

    float ssum = 0.f;
    for (int c = 0; c < nc; ++c) {
        int k = c * 64 + lane;
        if (k < deg) {
            int s = csr_src[base + k];
            float a = e_src[s] + edv;
            a = a > 0.f ? a : NEG_SLOPE * a;
            float ex = expf(a - m);
            coef2[base + k] = ex;
            ssum += ex;
        }
    }
#pragma unroll
    for (int o = 1; o < 64; o <<= 1) ssum += __shfl_xor(ssum, o);
    if (lane == 0) invden2[wid] = 1.f / ssum;
}

__global__ __launch_bounds__(256) void gather2_kernel(
    const int* __restrict__ rowptr, const int* __restrict__ csr_src,
    const float* __restrict__ h2, const float* __restrict__ coef2,
    const float* __restrict__ invden2, const float* __restrict__ b2,
    float* __restrict__ out, int N)
{
    int wid = (blockIdx.x * blockDim.x + threadIdx.x) >> 6;
    if (wid >= N) return;
    int lane = threadIdx.x & 63;
    int base = rowptr[wid], end = rowptr[wid + 1];
    float acc = 0.f;
    for (int j = base; j < end; ++j) {
        int s = csr_src[j];
        float c = coef2[j];
        if (lane < OUT_DIM) acc += c * h2[(size_t)s * OUT_DIM + lane];
    }
    if (lane < OUT_DIM)
        out[(size_t)wid * OUT_DIM + lane] = acc * invden2[wid] + b2[lane];
}

extern "C" void kernel_launch(void* const* d_in, const int* in_sizes, int n_in,
                              void* d_out, int out_size, void* d_ws, size_t ws_size,
                              hipStream_t stream)
{
    const float* x      = (const float*)d_in[0];
    const int*   ei     = (const int*)d_in[1];
    const float* W1     = (const float*)d_in[2];
    const float* a_src1 = (const float*)d_in[3];
    const float* a_dst1 = (const float*)d_in[4];
    const float* b1     = (const float*)d_in[5];
    const float* W2     = (const float*)d_in[6];
    const float* a_src2 = (const float*)d_in[7];
    const float* a_dst2 = (const float*)d_in[8];
    const float* b2     = (const float*)d_in[9];
    float* out = (float*)d_out;

    const int N  = in_sizes[0] / IN_DIM;   // 50000
    const int E  = in_sizes[1] / 2;        // 400000
    const int ET = E + N;                  // 450000

    // ---- workspace layout ----
    char* p = (char*)d_ws;
    auto alloc = [&](size_t bytes) -> void* {
        void* r = (void*)p;
        p += (bytes + 255) & ~(size_t)255;
        return r;
    };
    __hip_bfloat16* h1b    = (__hip_bfloat16*)alloc((size_t)N * HC1 * 2);
    __hip_bfloat16* hmid   = (__hip_bfloat16*)alloc((size_t)N * HC1 * 2);
    float*    h2      = (float*)alloc((size_t)N * OUT_DIM * 4);
    float*    e_src1  = (float*)alloc((size_t)N * HEADS * 4);
    float*    e_dst1  = (float*)alloc((size_t)N * HEADS * 4);
    float*    invden1 = (float*)alloc((size_t)N * HEADS * 4);
    float*    coef1   = (float*)alloc((size_t)ET * HEADS * 4);
    float*    e_src2  = (float*)alloc((size_t)N * 4);
    float*    e_dst2  = (float*)alloc((size_t)N * 4);
    float*    invden2 = (float*)alloc((size_t)N * 4);
    float*    coef2   = (float*)alloc((size_t)ET * 4);
    int*      deg     = (int*)alloc((size_t)N * 4);
    int*      rowptr  = (int*)alloc((size_t)(N + 1) * 4);
    int*      cursor  = (int*)alloc((size_t)N * 4);
    int*      csr_src = (int*)alloc((size_t)ET * 4);
    int*      aux     = (int*)alloc(256 * 4);
    __hip_bfloat16* W1T = (__hip_bfloat16*)alloc((size_t)HC1 * IN_DIM * 2);
    __hip_bfloat16* W2T = (__hip_bfloat16*)alloc((size_t)48 * HC1 * 2);

    const int nbN  = (N + 255) / 256;
    const int nbET = (ET + 255) / 256;

    // ---- weight prep ----
    prep_w1t<<<(HC1 * IN_DIM + 255) / 256, 256, 0, stream>>>(W1, W1T);
    prep_w2t<<<(48 * HC1 + 255) / 256, 256, 0, stream>>>(W2, W2T);

    // ---- CSR build ----
    hipMemsetAsync(deg, 0, (size_t)N * 4, stream);
    degree_kernel<<<nbET, 256, 0, stream>>>(ei, deg, E, ET);
    scan1_kernel<<<nbN, 256, 0, stream>>>(deg, rowptr, aux, N);
    scan_aux_kernel<<<1, 256, 0, stream>>>(aux, nbN);
    scan_add_kernel<<<nbN, 256, 0, stream>>>(rowptr, aux, N, ET);
    hipMemcpyAsync(cursor, rowptr, (size_t)N * 4, hipMemcpyDeviceToDevice, stream);
    build_kernel<<<nbET, 256, 0, stream>>>(ei, cursor, csr_src, E, ET);

    // ---- layer 1 ----
    gemm1_mfma<<<N / 16, 256, 0, stream>>>(x, W1T, a_src1, a_dst1, h1b,
                                           e_src1, e_dst1, N);
    softmax1_kernel<<<(N + 3) / 4, 256, 0, stream>>>(rowptr, csr_src, e_src1,
                                                     e_dst1, coef1, invden1, N);
    gather1_kernel<<<N, 256, 0, stream>>>(rowptr, csr_src, h1b, coef1, invden1,
                                          b1, hmid, N);

    // ---- layer 2 ----
    gemm2_mfma<<<(N + 63) / 64, 256, 0, stream>>>(hmid, W2T, a_src2, a_dst2, h2,
                                                  e_src2, e_dst2, N);
    softmax2_kernel<<<(N + 3) / 4, 256, 0, stream>>>(rowptr, csr_src, e_src2,
                                                     e_dst2, coef2, invden2, N);
    gather2_kernel<<<(N + 3) / 4, 256, 0, stream>>>(rowptr, csr_src, h2, coef2,
                                                    invden2, b2, out, N);
}

// Round 4
// 372.319 us; speedup vs baseline: 19.0051x; 1.1396x over previous
//
#include <hip/hip_runtime.h>
#include <hip/hip_bf16.h>
#include <math.h>

#define IN_DIM 256
#define HEADS 8
#define HID 64
#define HC1 512
#define OUT_DIM 40
#define NEG_SLOPE 0.2f

typedef __attribute__((ext_vector_type(8))) short short8;
typedef __attribute__((ext_vector_type(4))) float f32x4;

__device__ __forceinline__ unsigned short f2b(float f) {
    __hip_bfloat16 h = __float2bfloat16(f);
    unsigned short u;
    __builtin_memcpy(&u, &h, 2);
    return u;
}

// ================= weight prep =================

// W1 [256][512] f32 -> W1T [512][256] bf16
__global__ __launch_bounds__(256) void prep_w1t(
    const float* __restrict__ W1, __hip_bfloat16* __restrict__ W1T)
{
    int i = blockIdx.x * 256 + threadIdx.x;
    if (i >= HC1 * IN_DIM) return;
    int n = i >> 8, k = i & 255;
    W1T[i] = __float2bfloat16(W1[(size_t)k * HC1 + n]);
}

// W2 [512][40] f32 -> W2T [48][512] bf16 (zero-padded cols 40..47)
__global__ __launch_bounds__(256) void prep_w2t(
    const float* __restrict__ W2, __hip_bfloat16* __restrict__ W2T)
{
    int i = blockIdx.x * 256 + threadIdx.x;
    if (i >= 48 * HC1) return;
    int n = i >> 9, k = i & 511;
    W2T[i] = __float2bfloat16(n < OUT_DIM ? W2[(size_t)k * OUT_DIM + n] : 0.f);
}

// ================= CSR build =================

__global__ __launch_bounds__(256) void degree_kernel(
    const int* __restrict__ ei, int* __restrict__ deg, int E, int ET)
{
    int e = blockIdx.x * 256 + threadIdx.x;
    if (e >= ET) return;
    int d = (e < E) ? ei[E + e] : e - E;
    atomicAdd(&deg[d], 1);
}

__global__ __launch_bounds__(256) void scan1_kernel(
    const int* __restrict__ deg, int* __restrict__ rowptr,
    int* __restrict__ aux, int N)
{
    __shared__ int sd[256];
    int tid = threadIdx.x;
    int i = blockIdx.x * 256 + tid;
    int v = (i < N) ? deg[i] : 0;
    sd[tid] = v;
    __syncthreads();
    for (int off = 1; off < 256; off <<= 1) {
        int t = (tid >= off) ? sd[tid - off] : 0;
        __syncthreads();
        sd[tid] += t;
        __syncthreads();
    }
    if (i < N) rowptr[i] = sd[tid] - v;
    if (tid == 255) aux[blockIdx.x] = sd[255];
}

__global__ __launch_bounds__(256) void scan_aux_kernel(int* __restrict__ aux, int nb)
{
    __shared__ int sd[256];
    int tid = threadIdx.x;
    int v = (tid < nb) ? aux[tid] : 0;
    sd[tid] = v;
    __syncthreads();
    for (int off = 1; off < 256; off <<= 1) {
        int t = (tid >= off) ? sd[tid - off] : 0;
        __syncthreads();
        sd[tid] += t;
        __syncthreads();
    }
    if (tid < nb) aux[tid] = sd[tid] - v;
}

__global__ __launch_bounds__(256) void scan_add_kernel(
    int* __restrict__ rowptr, const int* __restrict__ aux, int N, int ET)
{
    int i = blockIdx.x * 256 + threadIdx.x;
    if (i < N) rowptr[i] += aux[blockIdx.x];
    if (i == 0) rowptr[N] = ET;
}

__global__ __launch_bounds__(256) void build_kernel(
    const int* __restrict__ ei, int* __restrict__ cursor,
    int* __restrict__ csr_src, int E, int ET)
{
    int e = blockIdx.x * 256 + threadIdx.x;
    if (e >= ET) return;
    int s, d;
    if (e < E) { s = ei[e]; d = ei[E + e]; } else { s = d = e - E; }
    int pos = atomicAdd(&cursor[d], 1);
    csr_src[pos] = s;
}

// ================= layer 1: MFMA GEMM, BM=64, LDS-staged A =================
// Block: 4 waves. A tile (64 rows x 256 K, bf16) in LDS, shared by all waves.
// Wave w: all 64 rows x cols [w*128, w*128+128) = heads 2w, 2w+1.
__global__ __launch_bounds__(256) void gemm1_mfma(
    const float* __restrict__ x, const __hip_bfloat16* __restrict__ W1T,
    const float* __restrict__ a_src1, const float* __restrict__ a_dst1,
    __hip_bfloat16* __restrict__ h1, float* __restrict__ e_src1,
    float* __restrict__ e_dst1, int N)
{
    __shared__ __hip_bfloat16 As[64][264];   // +8 pad: bank stride 4 -> 2-way (free)
    const int tid = threadIdx.x;
    const int row0 = blockIdx.x * 64;

    // ---- stage A: x f32 -> bf16 LDS ----
    {
        int rr = tid >> 2;                 // 0..63
        int cb = (tid & 3) * 64;           // 0/64/128/192
        int rowc = row0 + rr; if (rowc >= N) rowc = N - 1;
        const float* xp = x + (size_t)rowc * IN_DIM + cb;
#pragma unroll
        for (int j = 0; j < 8; ++j) {
            float4 a0 = *(const float4*)(xp + 8 * j);
            float4 a1 = *(const float4*)(xp + 8 * j + 4);
            short8 v;
            v[0] = f2b(a0.x); v[1] = f2b(a0.y); v[2] = f2b(a0.z); v[3] = f2b(a0.w);
            v[4] = f2b(a1.x); v[5] = f2b(a1.y); v[6] = f2b(a1.z); v[7] = f2b(a1.w);
            *(short8*)(&As[rr][cb + 8 * j]) = v;
        }
    }
    __syncthreads();

    const int w = tid >> 6;
    const int lane = tid & 63;
    const int r = lane & 15, g = lane >> 4;

    f32x4 acc[4][8] = {};
    const short* bp = (const short*)W1T + (size_t)(w * 128 + r) * IN_DIM + 8 * g;

#pragma unroll 2
    for (int kk = 0; kk < IN_DIM; kk += 32) {
        short8 af[4];
#pragma unroll
        for (int rt = 0; rt < 4; ++rt)
            af[rt] = *(const short8*)(&As[rt * 16 + r][kk + 8 * g]);
        short8 bf[8];
#pragma unroll
        for (int t = 0; t < 8; ++t)
            bf[t] = *(const short8*)(bp + (size_t)t * 16 * IN_DIM + kk);
#pragma unroll
        for (int t = 0; t < 8; ++t)
#pragma unroll
            for (int rt = 0; rt < 4; ++rt)
                acc[rt][t] = __builtin_amdgcn_mfma_f32_16x16x32_bf16(
                    af[rt], bf[t], acc[rt][t], 0, 0, 0);
    }

    // ---- store h1 ----
#pragma unroll
    for (int rt = 0; rt < 4; ++rt) {
#pragma unroll
        for (int t = 0; t < 8; ++t) {
            int c = w * 128 + t * 16 + r;
#pragma unroll
            for (int q = 0; q < 4; ++q) {
                int row = row0 + rt * 16 + 4 * g + q;
                if (row < N)
                    h1[(size_t)row * HC1 + c] = __float2bfloat16(acc[rt][t][q]);
            }
        }
    }

    // ---- fused logits (head hh per half of the 8 col-tiles) ----
#pragma unroll
    for (int hh = 0; hh < 2; ++hh) {
        float ps[4][4] = {}, pd[4][4] = {};
#pragma unroll
        for (int tt = 0; tt < 4; ++tt) {
            int t = hh * 4 + tt;
            int cc = (2 * w + hh) * HID + tt * 16 + r;
            float a1v = a_src1[cc];
            float a2v = a_dst1[cc];
#pragma unroll
            for (int rt = 0; rt < 4; ++rt)
#pragma unroll
                for (int q = 0; q < 4; ++q) {
                    ps[rt][q] += acc[rt][t][q] * a1v;
                    pd[rt][q] += acc[rt][t][q] * a2v;
                }
        }
#pragma unroll
        for (int off = 1; off < 16; off <<= 1)
#pragma unroll
            for (int rt = 0; rt < 4; ++rt)
#pragma unroll
                for (int q = 0; q < 4; ++q) {
                    ps[rt][q] += __shfl_xor(ps[rt][q], off);
                    pd[rt][q] += __shfl_xor(pd[rt][q], off);
                }
        if (r == 0) {
#pragma unroll
            for (int rt = 0; rt < 4; ++rt)
#pragma unroll
                for (int q = 0; q < 4; ++q) {
                    int row = row0 + rt * 16 + 4 * g + q;
                    if (row < N) {
                        e_src1[row * 8 + 2 * w + hh] = ps[rt][q];
                        e_dst1[row * 8 + 2 * w + hh] = pd[rt][q];
                    }
                }
        }
    }
}

// ================= softmax / gather layer 1 =================

__global__ __launch_bounds__(256) void softmax1_kernel(
    const int* __restrict__ rowptr, const int* __restrict__ csr_src,
    const float* __restrict__ e_src, const float* __restrict__ e_dst,
    float* __restrict__ coef, float* __restrict__ invden, int N)
{
    int wid = (blockIdx.x * blockDim.x + threadIdx.x) >> 6;
    if (wid >= N) return;
    int lane = threadIdx.x & 63;
    int i = lane >> 3, h = lane & 7;
    int base = rowptr[wid];
    int deg = rowptr[wid + 1] - base;
    float edv = e_dst[wid * 8 + h];
    int nc = (deg + 7) >> 3;

    float m = -INFINITY;
    for (int c = 0; c < nc; ++c) {
        int k = c * 8 + i;
        float a = -INFINITY;
        if (k < deg) {
            int s = csr_src[base + k];
            a = e_src[(size_t)s * 8 + h] + edv;
            a = a > 0.f ? a : NEG_SLOPE * a;
        }
        m = fmaxf(m, a);
    }
    m = fmaxf(m, __shfl_xor(m, 8));
    m = fmaxf(m, __shfl_xor(m, 16));
    m = fmaxf(m, __shfl_xor(m, 32));

    float ssum = 0.f;
    for (int c = 0; c < nc; ++c) {
        int k = c * 8 + i;
        if (k < deg) {
            int s = csr_src[base + k];
            float a = e_src[(size_t)s * 8 + h] + edv;
            a = a > 0.f ? a : NEG_SLOPE * a;
            float ex = expf(a - m);
            coef[(size_t)(base + k) * 8 + h] = ex;
            ssum += ex;
        }
    }
    ssum += __shfl_xor(ssum, 8);
    ssum += __shfl_xor(ssum, 16);
    ssum += __shfl_xor(ssum, 32);
    if (lane < 8) invden[wid * 8 + lane] = 1.f / ssum;
}

__global__ __launch_bounds__(256) void gather1_kernel(
    const int* __restrict__ rowptr, const int* __restrict__ csr_src,
    const __hip_bfloat16* __restrict__ h1, const float* __restrict__ coef,
    const float* __restrict__ invden, const float* __restrict__ b1,
    __hip_bfloat16* __restrict__ hmid, int N)
{
    int d = blockIdx.x;
    int t = threadIdx.x;
    int h0 = t >> 5;
    int base = rowptr[d], end = rowptr[d + 1];
    float acc0 = 0.f, acc1 = 0.f;
    for (int j = base; j < end; ++j) {
        int s = csr_src[j];
        float c = coef[(size_t)j * 8 + h0];
        unsigned uv = *(const unsigned*)(h1 + (size_t)s * HC1 + 2 * t);
        const __hip_bfloat16* hb = (const __hip_bfloat16*)&uv;
        acc0 += c * __bfloat162float(hb[0]);
        acc1 += c * __bfloat162float(hb[1]);
    }
    float inv = invden[d * 8 + h0];
    float o0 = acc0 * inv + b1[2 * t];
    float o1 = acc1 * inv + b1[2 * t + 1];
    o0 = o0 > 0.f ? o0 : expm1f(o0);
    o1 = o1 > 0.f ? o1 : expm1f(o1);
    __hip_bfloat16 rr[2] = { __float2bfloat16(o0), __float2bfloat16(o1) };
    *(unsigned*)(hmid + (size_t)d * HC1 + 2 * t) = *(unsigned*)rr;
}

// ================= layer 2: MFMA GEMM, BM=256, LDS-staged B =================
// Block: 4 waves. W2T (48 x 512 bf16) fully staged in LDS, shared.
// Wave w: rows [b*256 + w*64, +64) x 48 cols.
__global__ __launch_bounds__(256) void gemm2_mfma(
    const __hip_bfloat16* __restrict__ hmid, const __hip_bfloat16* __restrict__ W2T,
    const float* __restrict__ a_src2, const float* __restrict__ a_dst2,
    float* __restrict__ h2, float* __restrict__ e_src2, float* __restrict__ e_dst2,
    int N)
{
    __shared__ __hip_bfloat16 Bs[48][520];   // +8 pad
    const int tid = threadIdx.x;

    // ---- stage B ----
    {
        const short* wp = (const short*)W2T;
#pragma unroll
        for (int i = 0; i < 12; ++i) {
            int idx = tid + i * 256;           // 0..3071 chunks of 8 bf16
            int row = idx >> 6, ch = idx & 63;
            *(short8*)(&Bs[row][ch * 8]) = *(const short8*)(wp + (size_t)row * HC1 + ch * 8);
        }
    }
    __syncthreads();

    const int w = tid >> 6;
    const int lane = tid & 63;
    const int r = lane & 15, g = lane >> 4;
    const int rowW = blockIdx.x * 256 + w * 64;

    const short* ap[4];
#pragma unroll
    for (int rt = 0; rt < 4; ++rt) {
        int row = rowW + rt * 16 + r;
        if (row >= N) row = N - 1;
        ap[rt] = (const short*)hmid + (size_t)row * HC1 + 8 * g;
    }

    f32x4 acc[4][3] = {};
#pragma unroll 4
    for (int kk = 0; kk < HC1; kk += 32) {
        short8 af[4];
#pragma unroll
        for (int rt = 0; rt < 4; ++rt)
            af[rt] = *(const short8*)(ap[rt] + kk);
        short8 bf[3];
#pragma unroll
        for (int t = 0; t < 3; ++t)
            bf[t] = *(const short8*)(&Bs[t * 16 + r][kk + 8 * g]);
#pragma unroll
        for (int t = 0; t < 3; ++t)
#pragma unroll
            for (int rt = 0; rt < 4; ++rt)
                acc[rt][t] = __builtin_amdgcn_mfma_f32_16x16x32_bf16(
                    af[rt], bf[t], acc[rt][t], 0, 0, 0);
    }

    // ---- store h2 ----
#pragma unroll
    for (int rt = 0; rt < 4; ++rt)
#pragma unroll
        for (int t = 0; t < 3; ++t) {
            int c = t * 16 + r;
            if (c < OUT_DIM) {
#pragma unroll
                for (int q = 0; q < 4; ++q) {
                    int row = rowW + rt * 16 + 4 * g + q;
                    if (row < N) h2[(size_t)row * OUT_DIM + c] = acc[rt][t][q];
                }
            }
        }

    // ---- fused logits2 ----
    float as[3], ad[3];
#pragma unroll
    for (int t = 0; t < 3; ++t) {
        int c = t * 16 + r;
        as[t] = (c < OUT_DIM) ? a_src2[c] : 0.f;
        ad[t] = (c < OUT_DIM) ? a_dst2[c] : 0.f;
    }
    float ps[4][4] = {}, pd[4][4] = {};
#pragma unroll
    for (int t = 0; t < 3; ++t)
#pragma unroll
        for (int rt = 0; rt < 4; ++rt)
#pragma unroll
            for (int q = 0; q < 4; ++q) {
                ps[rt][q] += acc[rt][t][q] * as[t];
                pd[rt][q] += acc[rt][t][q] * ad[t];
            }
#pragma unroll
    for (int off = 1; off < 16; off <<= 1)
#pragma unroll
        for (int rt = 0; rt < 4; ++rt)
#pragma unroll
            for (int q = 0; q < 4; ++q) {
                ps[rt][q] += __shfl_xor(ps[rt][q], off);
                pd[rt][q] += __shfl_xor(pd[rt][q], off);
            }
    if (r == 0) {
#pragma unroll
        for (int rt = 0; rt < 4; ++rt)
#pragma unroll
            for (int q = 0; q < 4; ++q) {
                int row = rowW + rt * 16 + 4 * g + q;
                if (row < N) { e_src2[row] = ps[rt][q]; e_dst2[row] = pd[rt][q]; }
            }
    }
}

// ================= softmax / gather layer 2 =================

__global__ __launch_bounds__(256) void softmax2_kernel(
    const int* __restrict__ rowptr, const int* __restrict__ csr_src,
    const float* __restrict__ e_src, const float* __restrict__ e_dst,
    float* __restrict__ coef2, float* __restrict__ invden2, int N)
{
    int wid = (blockIdx.x * blockDim.x + threadIdx.x) >> 6;
    if (wid >= N) return;
    int lane = threadIdx.x & 63;
    int base = rowptr[wid];
    int deg = rowptr[wid + 1] - base;
    float edv = e_dst[wid];
    int nc = (deg + 63) >> 6;

    float m = -INFINITY;
    for (int c = 0; c < nc; ++c) {
        int k = c * 64 + lane;
        float a = -INFINITY;
        if (k < deg) {
            int s = csr_src[base + k];
            a = e_src[s] + edv;
            a = a > 0.f ? a : NEG_SLOPE * a;
        }
        m = fmaxf(m, a);
    }
#pragma unroll
    for (int o = 1; o < 64; o <<= 1) m = fmaxf(m, __shfl_xor(m, o));

    float ssum = 0.f;
    for (int c = 0; c < nc; ++c) {
        int k = c * 64 + lane;
        if (k < deg) {
            int s = csr_src[base + k];
            float a = e_src[s] + edv;
            a = a > 0.f ? a : NEG_SLOPE * a;
            float ex = expf(a - m);
            coef2[base + k] = ex;
            ssum += ex;
        }
    }
#pragma unroll
    for (int o = 1; o < 64; o <<= 1) ssum += __shfl_xor(ssum, o);
    if (lane == 0) invden2[wid] = 1.f / ssum;
}

__global__ __launch_bounds__(256) void gather2_kernel(
    const int* __restrict__ rowptr, const int* __restrict__ csr_src,
    const float* __restrict__ h2, const float* __restrict__ coef2,
    const float* __restrict__ invden2, const float* __restrict__ b2,
    float* __restrict__ out, int N)
{
    int wid = (blockIdx.x * blockDim.x + threadIdx.x) >> 6;
    if (wid >= N) return;
    int lane = threadIdx.x & 63;
    int base = rowptr[wid], end = rowptr[wid + 1];
    float acc = 0.f;
    for (int j = base; j < end; ++j) {
        int s = csr_src[j];
        float c = coef2[j];
        if (lane < OUT_DIM) acc += c * h2[(size_t)s * OUT_DIM + lane];
    }
    if (lane < OUT_DIM)
        out[(size_t)wid * OUT_DIM + lane] = acc * invden2[wid] + b2[lane];
}

extern "C" void kernel_launch(void* const* d_in, const int* in_sizes, int n_in,
                              void* d_out, int out_size, void* d_ws, size_t ws_size,
                              hipStream_t stream)
{
    const float* x      = (const float*)d_in[0];
    const int*   ei     = (const int*)d_in[1];
    const float* W1     = (const float*)d_in[2];
    const float* a_src1 = (const float*)d_in[3];
    const float* a_dst1 = (const float*)d_in[4];
    const float* b1     = (const float*)d_in[5];
    const float* W2     = (const float*)d_in[6];
    const float* a_src2 = (const float*)d_in[7];
    const float* a_dst2 = (const float*)d_in[8];
    const float* b2     = (const float*)d_in[9];
    float* out = (float*)d_out;

    const int N  = in_sizes[0] / IN_DIM;   // 50000
    const int E  = in_sizes[1] / 2;        // 400000
    const int ET = E + N;                  // 450000

    // ---- workspace layout ----
    char* p = (char*)d_ws;
    auto alloc = [&](size_t bytes) -> void* {
        void* r = (void*)p;
        p += (bytes + 255) & ~(size_t)255;
        return r;
    };
    __hip_bfloat16* h1b    = (__hip_bfloat16*)alloc((size_t)N * HC1 * 2);
    __hip_bfloat16* hmid   = (__hip_bfloat16*)alloc((size_t)N * HC1 * 2);
    float*    h2      = (float*)alloc((size_t)N * OUT_DIM * 4);
    float*    e_src1  = (float*)alloc((size_t)N * HEADS * 4);
    float*    e_dst1  = (float*)alloc((size_t)N * HEADS * 4);
    float*    invden1 = (float*)alloc((size_t)N * HEADS * 4);
    float*    coef1   = (float*)alloc((size_t)ET * HEADS * 4);
    float*    e_src2  = (float*)alloc((size_t)N * 4);
    float*    e_dst2  = (float*)alloc((size_t)N * 4);
    float*    invden2 = (float*)alloc((size_t)N * 4);
    float*    coef2   = (float*)alloc((size_t)ET * 4);
    int*      deg     = (int*)alloc((size_t)N * 4);
    int*      rowptr  = (int*)alloc((size_t)(N + 1) * 4);
    int*      cursor  = (int*)alloc((size_t)N * 4);
    int*      csr_src = (int*)alloc((size_t)ET * 4);
    int*      aux     = (int*)alloc(256 * 4);
    __hip_bfloat16* W1T = (__hip_bfloat16*)alloc((size_t)HC1 * IN_DIM * 2);
    __hip_bfloat16* W2T = (__hip_bfloat16*)alloc((size_t)48 * HC1 * 2);

    const int nbN  = (N + 255) / 256;
    const int nbET = (ET + 255) / 256;

    // ---- weight prep ----
    prep_w1t<<<(HC1 * IN_DIM + 255) / 256, 256, 0, stream>>>(W1, W1T);
    prep_w2t<<<(48 * HC1 + 255) / 256, 256, 0, stream>>>(W2, W2T);

    // ---- CSR build ----
    hipMemsetAsync(deg, 0, (size_t)N * 4, stream);
    degree_kernel<<<nbET, 256, 0, stream>>>(ei, deg, E, ET);
    scan1_kernel<<<nbN, 256, 0, stream>>>(deg, rowptr, aux, N);
    scan_aux_kernel<<<1, 256, 0, stream>>>(aux, nbN);
    scan_add_kernel<<<nbN, 256, 0, stream>>>(rowptr, aux, N, ET);
    hipMemcpyAsync(cursor, rowptr, (size_t)N * 4, hipMemcpyDeviceToDevice, stream);
    build_kernel<<<nbET, 256, 0, stream>>>(ei, cursor, csr_src, E, ET);

    // ---- layer 1 ----
    gemm1_mfma<<<(N + 63) / 64, 256, 0, stream>>>(x, W1T, a_src1, a_dst1, h1b,
                                                  e_src1, e_dst1, N);
    softmax1_kernel<<<(N + 3) / 4, 256, 0, stream>>>(rowptr, csr_src, e_src1,
                                                     e_dst1, coef1, invden1, N);
    gather1_kernel<<<N, 256, 0, stream>>>(rowptr, csr_src, h1b, coef1, invden1,
                                          b1, hmid, N);

    // ---- layer 2 ----
    gemm2_mfma<<<(N + 255) / 256, 256, 0, stream>>>(hmid, W2T, a_src2, a_dst2, h2,
                                                    e_src2, e_dst2, N);
    softmax2_kernel<<<(N + 3) / 4, 256, 0, stream>>>(rowptr, csr_src, e_src2,
                                                     e_dst2, coef2, invden2, N);
    gather2_kernel<<<(N + 3) / 4, 256, 0, stream>>>(rowptr, csr_src, h2, coef2,
                                                    invden2, b2, out, N);
}

// Round 5
// 273.446 us; speedup vs baseline: 25.8770x; 1.3616x over previous
//
#include <hip/hip_runtime.h>
#include <hip/hip_bf16.h>
#include <math.h>

#define IN_DIM 256
#define HEADS 8
#define HID 64
#define HC1 512
#define OUT_DIM 40
#define NEG_SLOPE 0.2f

typedef __attribute__((ext_vector_type(8))) short short8;
typedef __attribute__((ext_vector_type(4))) float f32x4;

__device__ __forceinline__ unsigned short f2b(float f) {
    __hip_bfloat16 h = __float2bfloat16(f);
    unsigned short u;
    __builtin_memcpy(&u, &h, 2);
    return u;
}

// ================= weight prep =================

__global__ __launch_bounds__(256) void prep_w1t(
    const float* __restrict__ W1, __hip_bfloat16* __restrict__ W1T)
{
    int i = blockIdx.x * 256 + threadIdx.x;
    if (i >= HC1 * IN_DIM) return;
    int n = i >> 8, k = i & 255;
    W1T[i] = __float2bfloat16(W1[(size_t)k * HC1 + n]);
}

__global__ __launch_bounds__(256) void prep_w2t(
    const float* __restrict__ W2, __hip_bfloat16* __restrict__ W2T)
{
    int i = blockIdx.x * 256 + threadIdx.x;
    if (i >= 48 * HC1) return;
    int n = i >> 9, k = i & 511;
    W2T[i] = __float2bfloat16(n < OUT_DIM ? W2[(size_t)k * OUT_DIM + n] : 0.f);
}

// ================= CSR build =================

__global__ __launch_bounds__(256) void degree_kernel(
    const int* __restrict__ ei, int* __restrict__ deg, int E, int ET)
{
    int e = blockIdx.x * 256 + threadIdx.x;
    if (e >= ET) return;
    int d = (e < E) ? ei[E + e] : e - E;
    atomicAdd(&deg[d], 1);
}

__global__ __launch_bounds__(256) void scan1_kernel(
    const int* __restrict__ deg, int* __restrict__ rowptr,
    int* __restrict__ aux, int N)
{
    __shared__ int sd[256];
    int tid = threadIdx.x;
    int i = blockIdx.x * 256 + tid;
    int v = (i < N) ? deg[i] : 0;
    sd[tid] = v;
    __syncthreads();
    for (int off = 1; off < 256; off <<= 1) {
        int t = (tid >= off) ? sd[tid - off] : 0;
        __syncthreads();
        sd[tid] += t;
        __syncthreads();
    }
    if (i < N) rowptr[i] = sd[tid] - v;
    if (tid == 255) aux[blockIdx.x] = sd[255];
}

__global__ __launch_bounds__(256) void scan_aux_kernel(int* __restrict__ aux, int nb)
{
    __shared__ int sd[256];
    int tid = threadIdx.x;
    int v = (tid < nb) ? aux[tid] : 0;
    sd[tid] = v;
    __syncthreads();
    for (int off = 1; off < 256; off <<= 1) {
        int t = (tid >= off) ? sd[tid - off] : 0;
        __syncthreads();
        sd[tid] += t;
        __syncthreads();
    }
    if (tid < nb) aux[tid] = sd[tid] - v;
}

__global__ __launch_bounds__(256) void scan_add_kernel(
    int* __restrict__ rowptr, const int* __restrict__ aux, int N, int ET)
{
    int i = blockIdx.x * 256 + threadIdx.x;
    if (i < N) rowptr[i] += aux[blockIdx.x];
    if (i == 0) rowptr[N] = ET;
}

__global__ __launch_bounds__(256) void build_kernel(
    const int* __restrict__ ei, int* __restrict__ cursor,
    int* __restrict__ csr_src, int E, int ET)
{
    int e = blockIdx.x * 256 + threadIdx.x;
    if (e >= ET) return;
    int s, d;
    if (e < E) { s = ei[e]; d = ei[E + e]; } else { s = d = e - E; }
    int pos = atomicAdd(&cursor[d], 1);
    csr_src[pos] = s;
}

// ================= layer 1: MFMA GEMM, BM=64, LDS-staged A =================

__global__ __launch_bounds__(256) void gemm1_mfma(
    const float* __restrict__ x, const __hip_bfloat16* __restrict__ W1T,
    const float* __restrict__ a_src1, const float* __restrict__ a_dst1,
    __hip_bfloat16* __restrict__ h1, float* __restrict__ e_src1,
    float* __restrict__ e_dst1, int N)
{
    __shared__ __hip_bfloat16 As[64][264];
    const int tid = threadIdx.x;
    const int row0 = blockIdx.x * 64;

    {
        int rr = tid >> 2;
        int cb = (tid & 3) * 64;
        int rowc = row0 + rr; if (rowc >= N) rowc = N - 1;
        const float* xp = x + (size_t)rowc * IN_DIM + cb;
#pragma unroll
        for (int j = 0; j < 8; ++j) {
            float4 a0 = *(const float4*)(xp + 8 * j);
            float4 a1 = *(const float4*)(xp + 8 * j + 4);
            short8 v;
            v[0] = f2b(a0.x); v[1] = f2b(a0.y); v[2] = f2b(a0.z); v[3] = f2b(a0.w);
            v[4] = f2b(a1.x); v[5] = f2b(a1.y); v[6] = f2b(a1.z); v[7] = f2b(a1.w);
            *(short8*)(&As[rr][cb + 8 * j]) = v;
        }
    }
    __syncthreads();

    const int w = tid >> 6;
    const int lane = tid & 63;
    const int r = lane & 15, g = lane >> 4;

    f32x4 acc[4][8] = {};
    const short* bp = (const short*)W1T + (size_t)(w * 128 + r) * IN_DIM + 8 * g;

#pragma unroll 2
    for (int kk = 0; kk < IN_DIM; kk += 32) {
        short8 af[4];
#pragma unroll
        for (int rt = 0; rt < 4; ++rt)
            af[rt] = *(const short8*)(&As[rt * 16 + r][kk + 8 * g]);
        short8 bf[8];
#pragma unroll
        for (int t = 0; t < 8; ++t)
            bf[t] = *(const short8*)(bp + (size_t)t * 16 * IN_DIM + kk);
#pragma unroll
        for (int t = 0; t < 8; ++t)
#pragma unroll
            for (int rt = 0; rt < 4; ++rt)
                acc[rt][t] = __builtin_amdgcn_mfma_f32_16x16x32_bf16(
                    af[rt], bf[t], acc[rt][t], 0, 0, 0);
    }

#pragma unroll
    for (int rt = 0; rt < 4; ++rt) {
#pragma unroll
        for (int t = 0; t < 8; ++t) {
            int c = w * 128 + t * 16 + r;
#pragma unroll
            for (int q = 0; q < 4; ++q) {
                int row = row0 + rt * 16 + 4 * g + q;
                if (row < N)
                    h1[(size_t)row * HC1 + c] = __float2bfloat16(acc[rt][t][q]);
            }
        }
    }

#pragma unroll
    for (int hh = 0; hh < 2; ++hh) {
        float ps[4][4] = {}, pd[4][4] = {};
#pragma unroll
        for (int tt = 0; tt < 4; ++tt) {
            int t = hh * 4 + tt;
            int cc = (2 * w + hh) * HID + tt * 16 + r;
            float a1v = a_src1[cc];
            float a2v = a_dst1[cc];
#pragma unroll
            for (int rt = 0; rt < 4; ++rt)
#pragma unroll
                for (int q = 0; q < 4; ++q) {
                    ps[rt][q] += acc[rt][t][q] * a1v;
                    pd[rt][q] += acc[rt][t][q] * a2v;
                }
        }
#pragma unroll
        for (int off = 1; off < 16; off <<= 1)
#pragma unroll
            for (int rt = 0; rt < 4; ++rt)
#pragma unroll
                for (int q = 0; q < 4; ++q) {
                    ps[rt][q] += __shfl_xor(ps[rt][q], off);
                    pd[rt][q] += __shfl_xor(pd[rt][q], off);
                }
        if (r == 0) {
#pragma unroll
            for (int rt = 0; rt < 4; ++rt)
#pragma unroll
                for (int q = 0; q < 4; ++q) {
                    int row = row0 + rt * 16 + 4 * g + q;
                    if (row < N) {
                        e_src1[row * 8 + 2 * w + hh] = ps[rt][q];
                        e_dst1[row * 8 + 2 * w + hh] = pd[rt][q];
                    }
                }
        }
    }
}

// ================= gather layer 1 (inline softmax, no max-shift) =================
// 2 nodes per 256-thread block; thread t (0..127) owns features 4t..4t+3, head t>>4.
// exp(a) unnormalized; every thread in a head-group computes the identical ex,
// so ssum needs no cross-lane reduction.
__global__ __launch_bounds__(256) void gather1_kernel(
    const int* __restrict__ rowptr, const int* __restrict__ csr_src,
    const __hip_bfloat16* __restrict__ h1, const float* __restrict__ e_src,
    const float* __restrict__ e_dst, const float* __restrict__ b1,
    __hip_bfloat16* __restrict__ hmid, int N)
{
    int d = blockIdx.x * 2 + (threadIdx.x >> 7);
    if (d >= N) return;
    int t = threadIdx.x & 127;
    int h0 = t >> 4;
    int base = rowptr[d], end = rowptr[d + 1];
    float ed = e_dst[d * 8 + h0];

    float a0f = 0.f, a1f = 0.f, a2f = 0.f, a3f = 0.f, ssum = 0.f;

#define LRELU(a) ((a) > 0.f ? (a) : NEG_SLOPE * (a))
#define ACCUM(u, e)                                          \
    {                                                        \
        a0f += (e) * __uint_as_float((u).x << 16);           \
        a1f += (e) * __uint_as_float((u).x & 0xffff0000u);   \
        a2f += (e) * __uint_as_float((u).y << 16);           \
        a3f += (e) * __uint_as_float((u).y & 0xffff0000u);   \
        ssum += (e);                                         \
    }

    int j = base;
    for (; j + 4 <= end; j += 4) {
        int s0 = csr_src[j], s1 = csr_src[j + 1], s2 = csr_src[j + 2], s3 = csr_src[j + 3];
        float v0 = e_src[s0 * 8 + h0] + ed;
        float v1 = e_src[s1 * 8 + h0] + ed;
        float v2 = e_src[s2 * 8 + h0] + ed;
        float v3 = e_src[s3 * 8 + h0] + ed;
        uint2 u0 = *(const uint2*)(h1 + (size_t)s0 * HC1 + 4 * t);
        uint2 u1 = *(const uint2*)(h1 + (size_t)s1 * HC1 + 4 * t);
        uint2 u2 = *(const uint2*)(h1 + (size_t)s2 * HC1 + 4 * t);
        uint2 u3 = *(const uint2*)(h1 + (size_t)s3 * HC1 + 4 * t);
        float e0 = __expf(LRELU(v0));
        float e1 = __expf(LRELU(v1));
        float e2 = __expf(LRELU(v2));
        float e3 = __expf(LRELU(v3));
        ACCUM(u0, e0); ACCUM(u1, e1); ACCUM(u2, e2); ACCUM(u3, e3);
    }
    for (; j < end; ++j) {
        int s0 = csr_src[j];
        float v0 = e_src[s0 * 8 + h0] + ed;
        uint2 u0 = *(const uint2*)(h1 + (size_t)s0 * HC1 + 4 * t);
        float e0 = __expf(LRELU(v0));
        ACCUM(u0, e0);
    }

    float inv = 1.f / ssum;
    const float4 bv = *(const float4*)(b1 + 4 * t);
    float o0 = a0f * inv + bv.x;
    float o1 = a1f * inv + bv.y;
    float o2 = a2f * inv + bv.z;
    float o3 = a3f * inv + bv.w;
    o0 = o0 > 0.f ? o0 : expm1f(o0);
    o1 = o1 > 0.f ? o1 : expm1f(o1);
    o2 = o2 > 0.f ? o2 : expm1f(o2);
    o3 = o3 > 0.f ? o3 : expm1f(o3);
    unsigned short rr[4] = { f2b(o0), f2b(o1), f2b(o2), f2b(o3) };
    *(uint2*)(hmid + (size_t)d * HC1 + 4 * t) = *(uint2*)rr;
}

// ================= layer 2: MFMA GEMM, BM=256, LDS-staged B =================

__global__ __launch_bounds__(256) void gemm2_mfma(
    const __hip_bfloat16* __restrict__ hmid, const __hip_bfloat16* __restrict__ W2T,
    const float* __restrict__ a_src2, const float* __restrict__ a_dst2,
    float* __restrict__ h2, float* __restrict__ e_src2, float* __restrict__ e_dst2,
    int N)
{
    __shared__ __hip_bfloat16 Bs[48][520];
    const int tid = threadIdx.x;

    {
        const short* wp = (const short*)W2T;
#pragma unroll
        for (int i = 0; i < 12; ++i) {
            int idx = tid + i * 256;
            int row = idx >> 6, ch = idx & 63;
            *(short8*)(&Bs[row][ch * 8]) = *(const short8*)(wp + (size_t)row * HC1 + ch * 8);
        }
    }
    __syncthreads();

    const int w = tid >> 6;
    const int lane = tid & 63;
    const int r = lane & 15, g = lane >> 4;
    const int rowW = blockIdx.x * 256 + w * 64;

    const short* ap[4];
#pragma unroll
    for (int rt = 0; rt < 4; ++rt) {
        int row = rowW + rt * 16 + r;
        if (row >= N) row = N - 1;
        ap[rt] = (const short*)hmid + (size_t)row * HC1 + 8 * g;
    }

    f32x4 acc[4][3] = {};
#pragma unroll 4
    for (int kk = 0; kk < HC1; kk += 32) {
        short8 af[4];
#pragma unroll
        for (int rt = 0; rt < 4; ++rt)
            af[rt] = *(const short8*)(ap[rt] + kk);
        short8 bf[3];
#pragma unroll
        for (int t = 0; t < 3; ++t)
            bf[t] = *(const short8*)(&Bs[t * 16 + r][kk + 8 * g]);
#pragma unroll
        for (int t = 0; t < 3; ++t)
#pragma unroll
            for (int rt = 0; rt < 4; ++rt)
                acc[rt][t] = __builtin_amdgcn_mfma_f32_16x16x32_bf16(
                    af[rt], bf[t], acc[rt][t], 0, 0, 0);
    }

#pragma unroll
    for (int rt = 0; rt < 4; ++rt)
#pragma unroll
        for (int t = 0; t < 3; ++t) {
            int c = t * 16 + r;
            if (c < OUT_DIM) {
#pragma unroll
                for (int q = 0; q < 4; ++q) {
                    int row = rowW + rt * 16 + 4 * g + q;
                    if (row < N) h2[(size_t)row * OUT_DIM + c] = acc[rt][t][q];
                }
            }
        }

    float as[3], ad[3];
#pragma unroll
    for (int t = 0; t < 3; ++t) {
        int c = t * 16 + r;
        as[t] = (c < OUT_DIM) ? a_src2[c] : 0.f;
        ad[t] = (c < OUT_DIM) ? a_dst2[c] : 0.f;
    }
    float ps[4][4] = {}, pd[4][4] = {};
#pragma unroll
    for (int t = 0; t < 3; ++t)
#pragma unroll
        for (int rt = 0; rt < 4; ++rt)
#pragma unroll
            for (int q = 0; q < 4; ++q) {
                ps[rt][q] += acc[rt][t][q] * as[t];
                pd[rt][q] += acc[rt][t][q] * ad[t];
            }
#pragma unroll
    for (int off = 1; off < 16; off <<= 1)
#pragma unroll
        for (int rt = 0; rt < 4; ++rt)
#pragma unroll
            for (int q = 0; q < 4; ++q) {
                ps[rt][q] += __shfl_xor(ps[rt][q], off);
                pd[rt][q] += __shfl_xor(pd[rt][q], off);
            }
    if (r == 0) {
#pragma unroll
        for (int rt = 0; rt < 4; ++rt)
#pragma unroll
            for (int q = 0; q < 4; ++q) {
                int row = rowW + rt * 16 + 4 * g + q;
                if (row < N) { e_src2[row] = ps[rt][q]; e_dst2[row] = pd[rt][q]; }
            }
    }
}

// ================= gather layer 2 (inline softmax) =================
// One wave per dst node; lane<40 = feature.
__global__ __launch_bounds__(256) void gather2_kernel(
    const int* __restrict__ rowptr, const int* __restrict__ csr_src,
    const float* __restrict__ h2, const float* __restrict__ e_src,
    const float* __restrict__ e_dst, const float* __restrict__ b2,
    float* __restrict__ out, int N)
{
    int wid = (blockIdx.x * blockDim.x + threadIdx.x) >> 6;
    if (wid >= N) return;
    int lane = threadIdx.x & 63;
    int base = rowptr[wid], end = rowptr[wid + 1];
    float ed = e_dst[wid];
    bool act = lane < OUT_DIM;
    int ln = act ? lane : 0;

    float acc = 0.f, ssum = 0.f;
    int j = base;
    for (; j + 4 <= end; j += 4) {
        int s0 = csr_src[j], s1 = csr_src[j + 1], s2 = csr_src[j + 2], s3 = csr_src[j + 3];
        float v0 = e_src[s0] + ed, v1 = e_src[s1] + ed;
        float v2 = e_src[s2] + ed, v3 = e_src[s3] + ed;
        float f0 = h2[(size_t)s0 * OUT_DIM + ln];
        float f1 = h2[(size_t)s1 * OUT_DIM + ln];
        float f2 = h2[(size_t)s2 * OUT_DIM + ln];
        float f3 = h2[(size_t)s3 * OUT_DIM + ln];
        float e0 = __expf(LRELU(v0)), e1 = __expf(LRELU(v1));
        float e2 = __expf(LRELU(v2)), e3 = __expf(LRELU(v3));
        acc += e0 * f0 + e1 * f1 + e2 * f2 + e3 * f3;
        ssum += e0 + e1 + e2 + e3;
    }
    for (; j < end; ++j) {
        int s0 = csr_src[j];
        float v0 = e_src[s0] + ed;
        float f0 = h2[(size_t)s0 * OUT_DIM + ln];
        float e0 = __expf(LRELU(v0));
        acc += e0 * f0;
        ssum += e0;
    }
    if (act)
        out[(size_t)wid * OUT_DIM + lane] = acc / ssum + b2[lane];
}

extern "C" void kernel_launch(void* const* d_in, const int* in_sizes, int n_in,
                              void* d_out, int out_size, void* d_ws, size_t ws_size,
                              hipStream_t stream)
{
    const float* x      = (const float*)d_in[0];
    const int*   ei     = (const int*)d_in[1];
    const float* W1     = (const float*)d_in[2];
    const float* a_src1 = (const float*)d_in[3];
    const float* a_dst1 = (const float*)d_in[4];
    const float* b1     = (const float*)d_in[5];
    const float* W2     = (const float*)d_in[6];
    const float* a_src2 = (const float*)d_in[7];
    const float* a_dst2 = (const float*)d_in[8];
    const float* b2     = (const float*)d_in[9];
    float* out = (float*)d_out;

    const int N  = in_sizes[0] / IN_DIM;   // 50000
    const int E  = in_sizes[1] / 2;        // 400000
    const int ET = E + N;                  // 450000

    char* p = (char*)d_ws;
    auto alloc = [&](size_t bytes) -> void* {
        void* r = (void*)p;
        p += (bytes + 255) & ~(size_t)255;
        return r;
    };
    __hip_bfloat16* h1b    = (__hip_bfloat16*)alloc((size_t)N * HC1 * 2);
    __hip_bfloat16* hmid   = (__hip_bfloat16*)alloc((size_t)N * HC1 * 2);
    float*    h2      = (float*)alloc((size_t)N * OUT_DIM * 4);
    float*    e_src1  = (float*)alloc((size_t)N * HEADS * 4);
    float*    e_dst1  = (float*)alloc((size_t)N * HEADS * 4);
    float*    e_src2  = (float*)alloc((size_t)N * 4);
    float*    e_dst2  = (float*)alloc((size_t)N * 4);
    int*      deg     = (int*)alloc((size_t)N * 4);
    int*      rowptr  = (int*)alloc((size_t)(N + 1) * 4);
    int*      cursor  = (int*)alloc((size_t)N * 4);
    int*      csr_src = (int*)alloc((size_t)ET * 4);
    int*      aux     = (int*)alloc(256 * 4);
    __hip_bfloat16* W1T = (__hip_bfloat16*)alloc((size_t)HC1 * IN_DIM * 2);
    __hip_bfloat16* W2T = (__hip_bfloat16*)alloc((size_t)48 * HC1 * 2);

    const int nbN  = (N + 255) / 256;
    const int nbET = (ET + 255) / 256;

    // ---- weight prep ----
    prep_w1t<<<(HC1 * IN_DIM + 255) / 256, 256, 0, stream>>>(W1, W1T);
    prep_w2t<<<(48 * HC1 + 255) / 256, 256, 0, stream>>>(W2, W2T);

    // ---- CSR build ----
    hipMemsetAsync(deg, 0, (size_t)N * 4, stream);
    degree_kernel<<<nbET, 256, 0, stream>>>(ei, deg, E, ET);
    scan1_kernel<<<nbN, 256, 0, stream>>>(deg, rowptr, aux, N);
    scan_aux_kernel<<<1, 256, 0, stream>>>(aux, nbN);
    scan_add_kernel<<<nbN, 256, 0, stream>>>(rowptr, aux, N, ET);
    hipMemcpyAsync(cursor, rowptr, (size_t)N * 4, hipMemcpyDeviceToDevice, stream);
    build_kernel<<<nbET, 256, 0, stream>>>(ei, cursor, csr_src, E, ET);

    // ---- layer 1 ----
    gemm1_mfma<<<(N + 63) / 64, 256, 0, stream>>>(x, W1T, a_src1, a_dst1, h1b,
                                                  e_src1, e_dst1, N);
    gather1_kernel<<<(N + 1) / 2, 256, 0, stream>>>(rowptr, csr_src, h1b, e_src1,
                                                    e_dst1, b1, hmid, N);

    // ---- layer 2 ----
    gemm2_mfma<<<(N + 255) / 256, 256, 0, stream>>>(hmid, W2T, a_src2, a_dst2, h2,
                                                    e_src2, e_dst2, N);
    gather2_kernel<<<(N + 3) / 4, 256, 0, stream>>>(rowptr, csr_src, h2, e_src2,
                                                    e_dst2, b2, out, N);
}

// Round 6
// 240.811 us; speedup vs baseline: 29.3838x; 1.1355x over previous
//
#include <hip/hip_runtime.h>
#include <hip/hip_bf16.h>
#include <math.h>

#define IN_DIM 256
#define HEADS 8
#define HID 64
#define HC1 512
#define OUT_DIM 40
#define NEG_SLOPE 0.2f

typedef __attribute__((ext_vector_type(8))) short short8;
typedef __attribute__((ext_vector_type(4))) float f32x4;

__device__ __forceinline__ unsigned short f2b(float f) {
    __hip_bfloat16 h = __float2bfloat16(f);
    unsigned short u;
    __builtin_memcpy(&u, &h, 2);
    return u;
}

// ================= weight prep =================

__global__ __launch_bounds__(256) void prep_w1t(
    const float* __restrict__ W1, __hip_bfloat16* __restrict__ W1T)
{
    int i = blockIdx.x * 256 + threadIdx.x;
    if (i >= HC1 * IN_DIM) return;
    int n = i >> 8, k = i & 255;
    W1T[i] = __float2bfloat16(W1[(size_t)k * HC1 + n]);
}

__global__ __launch_bounds__(256) void prep_w2t(
    const float* __restrict__ W2, __hip_bfloat16* __restrict__ W2T)
{
    int i = blockIdx.x * 256 + threadIdx.x;
    if (i >= 48 * HC1) return;
    int n = i >> 9, k = i & 511;
    W2T[i] = __float2bfloat16(n < OUT_DIM ? W2[(size_t)k * OUT_DIM + n] : 0.f);
}

// ================= CSR build =================

__global__ __launch_bounds__(256) void degree_kernel(
    const int* __restrict__ ei, int* __restrict__ deg, int E, int ET)
{
    int e = blockIdx.x * 256 + threadIdx.x;
    if (e >= ET) return;
    int d = (e < E) ? ei[E + e] : e - E;
    atomicAdd(&deg[d], 1);
}

__global__ __launch_bounds__(256) void scan1_kernel(
    const int* __restrict__ deg, int* __restrict__ rowptr,
    int* __restrict__ aux, int N)
{
    __shared__ int sd[256];
    int tid = threadIdx.x;
    int i = blockIdx.x * 256 + tid;
    int v = (i < N) ? deg[i] : 0;
    sd[tid] = v;
    __syncthreads();
    for (int off = 1; off < 256; off <<= 1) {
        int t = (tid >= off) ? sd[tid - off] : 0;
        __syncthreads();
        sd[tid] += t;
        __syncthreads();
    }
    if (i < N) rowptr[i] = sd[tid] - v;
    if (tid == 255) aux[blockIdx.x] = sd[255];
}

__global__ __launch_bounds__(256) void scan_aux_kernel(int* __restrict__ aux, int nb)
{
    __shared__ int sd[256];
    int tid = threadIdx.x;
    int v = (tid < nb) ? aux[tid] : 0;
    sd[tid] = v;
    __syncthreads();
    for (int off = 1; off < 256; off <<= 1) {
        int t = (tid >= off) ? sd[tid - off] : 0;
        __syncthreads();
        sd[tid] += t;
        __syncthreads();
    }
    if (tid < nb) aux[tid] = sd[tid] - v;
}

__global__ __launch_bounds__(256) void scan_add_kernel(
    int* __restrict__ rowptr, const int* __restrict__ aux, int N, int ET)
{
    int i = blockIdx.x * 256 + threadIdx.x;
    if (i < N) rowptr[i] += aux[blockIdx.x];
    if (i == 0) rowptr[N] = ET;
}

__global__ __launch_bounds__(256) void build_kernel(
    const int* __restrict__ ei, int* __restrict__ cursor,
    int* __restrict__ csr_src, int E, int ET)
{
    int e = blockIdx.x * 256 + threadIdx.x;
    if (e >= ET) return;
    int s, d;
    if (e < E) { s = ei[e]; d = ei[E + e]; } else { s = d = e - E; }
    int pos = atomicAdd(&cursor[d], 1);
    csr_src[pos] = s;
}

// ================= layer 1: MFMA GEMM =================
// 512 threads = 8 waves. Block: 64 rows x 512 cols. Wave w: 64 rows x 64 cols
// = exactly head w. acc[4][4] = 64 AGPRs (occupancy: ~3 waves/SIMD).
__global__ __launch_bounds__(512) void gemm1_mfma(
    const float* __restrict__ x, const __hip_bfloat16* __restrict__ W1T,
    const float* __restrict__ a_src1, const float* __restrict__ a_dst1,
    __hip_bfloat16* __restrict__ h1, float* __restrict__ e_src1,
    float* __restrict__ e_dst1, int N)
{
    __shared__ __hip_bfloat16 As[64][264];
    const int tid = threadIdx.x;
    const int row0 = blockIdx.x * 64;

    // ---- stage A: 64x256 f32 -> bf16 LDS (each thread 32 cols of one row) ----
    {
        int rr = tid >> 3;
        int cb = (tid & 7) * 32;
        int rowc = row0 + rr; if (rowc >= N) rowc = N - 1;
        const float* xp = x + (size_t)rowc * IN_DIM + cb;
#pragma unroll
        for (int j = 0; j < 4; ++j) {
            float4 a0 = *(const float4*)(xp + 8 * j);
            float4 a1 = *(const float4*)(xp + 8 * j + 4);
            short8 v;
            v[0] = f2b(a0.x); v[1] = f2b(a0.y); v[2] = f2b(a0.z); v[3] = f2b(a0.w);
            v[4] = f2b(a1.x); v[5] = f2b(a1.y); v[6] = f2b(a1.z); v[7] = f2b(a1.w);
            *(short8*)(&As[rr][cb + 8 * j]) = v;
        }
    }
    __syncthreads();

    const int w = tid >> 6;          // 0..7 = head index
    const int lane = tid & 63;
    const int r = lane & 15, g = lane >> 4;

    f32x4 acc[4][4] = {};
    const short* bp = (const short*)W1T + (size_t)(w * 64 + r) * IN_DIM + 8 * g;

#pragma unroll 2
    for (int kk = 0; kk < IN_DIM; kk += 32) {
        short8 af[4];
#pragma unroll
        for (int rt = 0; rt < 4; ++rt)
            af[rt] = *(const short8*)(&As[rt * 16 + r][kk + 8 * g]);
        short8 bf[4];
#pragma unroll
        for (int t = 0; t < 4; ++t)
            bf[t] = *(const short8*)(bp + (size_t)t * 16 * IN_DIM + kk);
#pragma unroll
        for (int t = 0; t < 4; ++t)
#pragma unroll
            for (int rt = 0; rt < 4; ++rt)
                acc[rt][t] = __builtin_amdgcn_mfma_f32_16x16x32_bf16(
                    af[rt], bf[t], acc[rt][t], 0, 0, 0);
    }

    // ---- store h1 ----
#pragma unroll
    for (int rt = 0; rt < 4; ++rt)
#pragma unroll
        for (int t = 0; t < 4; ++t) {
            int c = w * 64 + t * 16 + r;
#pragma unroll
            for (int q = 0; q < 4; ++q) {
                int row = row0 + rt * 16 + 4 * g + q;
                if (row < N)
                    h1[(size_t)row * HC1 + c] = __float2bfloat16(acc[rt][t][q]);
            }
        }

    // ---- fused logits for head w (sequential per rt to cap registers) ----
    float a1v[4], a2v[4];
#pragma unroll
    for (int t = 0; t < 4; ++t) {
        a1v[t] = a_src1[w * 64 + t * 16 + r];
        a2v[t] = a_dst1[w * 64 + t * 16 + r];
    }
#pragma unroll
    for (int rt = 0; rt < 4; ++rt) {
        float ps[4] = {}, pd[4] = {};
#pragma unroll
        for (int t = 0; t < 4; ++t)
#pragma unroll
            for (int q = 0; q < 4; ++q) {
                ps[q] += acc[rt][t][q] * a1v[t];
                pd[q] += acc[rt][t][q] * a2v[t];
            }
#pragma unroll
        for (int off = 1; off < 16; off <<= 1)
#pragma unroll
            for (int q = 0; q < 4; ++q) {
                ps[q] += __shfl_xor(ps[q], off);
                pd[q] += __shfl_xor(pd[q], off);
            }
        if (r == 0) {
#pragma unroll
            for (int q = 0; q < 4; ++q) {
                int row = row0 + rt * 16 + 4 * g + q;
                if (row < N) {
                    e_src1[row * 8 + w] = ps[q];
                    e_dst1[row * 8 + w] = pd[q];
                }
            }
        }
    }
}

// ================= gather layer 1 (inline softmax, no max-shift) =================
__global__ __launch_bounds__(256) void gather1_kernel(
    const int* __restrict__ rowptr, const int* __restrict__ csr_src,
    const __hip_bfloat16* __restrict__ h1, const float* __restrict__ e_src,
    const float* __restrict__ e_dst, const float* __restrict__ b1,
    __hip_bfloat16* __restrict__ hmid, int N)
{
    int d = blockIdx.x * 2 + (threadIdx.x >> 7);
    if (d >= N) return;
    int t = threadIdx.x & 127;
    int h0 = t >> 4;
    int base = rowptr[d], end = rowptr[d + 1];
    float ed = e_dst[d * 8 + h0];

    float a0f = 0.f, a1f = 0.f, a2f = 0.f, a3f = 0.f, ssum = 0.f;

#define LRELU(a) ((a) > 0.f ? (a) : NEG_SLOPE * (a))
#define ACCUM(u, e)                                          \
    {                                                        \
        a0f += (e) * __uint_as_float((u).x << 16);           \
        a1f += (e) * __uint_as_float((u).x & 0xffff0000u);   \
        a2f += (e) * __uint_as_float((u).y << 16);           \
        a3f += (e) * __uint_as_float((u).y & 0xffff0000u);   \
        ssum += (e);                                         \
    }

    int j = base;
    for (; j + 4 <= end; j += 4) {
        int s0 = csr_src[j], s1 = csr_src[j + 1], s2 = csr_src[j + 2], s3 = csr_src[j + 3];
        float v0 = e_src[s0 * 8 + h0] + ed;
        float v1 = e_src[s1 * 8 + h0] + ed;
        float v2 = e_src[s2 * 8 + h0] + ed;
        float v3 = e_src[s3 * 8 + h0] + ed;
        uint2 u0 = *(const uint2*)(h1 + (size_t)s0 * HC1 + 4 * t);
        uint2 u1 = *(const uint2*)(h1 + (size_t)s1 * HC1 + 4 * t);
        uint2 u2 = *(const uint2*)(h1 + (size_t)s2 * HC1 + 4 * t);
        uint2 u3 = *(const uint2*)(h1 + (size_t)s3 * HC1 + 4 * t);
        float e0 = __expf(LRELU(v0));
        float e1 = __expf(LRELU(v1));
        float e2 = __expf(LRELU(v2));
        float e3 = __expf(LRELU(v3));
        ACCUM(u0, e0); ACCUM(u1, e1); ACCUM(u2, e2); ACCUM(u3, e3);
    }
    for (; j < end; ++j) {
        int s0 = csr_src[j];
        float v0 = e_src[s0 * 8 + h0] + ed;
        uint2 u0 = *(const uint2*)(h1 + (size_t)s0 * HC1 + 4 * t);
        float e0 = __expf(LRELU(v0));
        ACCUM(u0, e0);
    }

    float inv = 1.f / ssum;
    const float4 bv = *(const float4*)(b1 + 4 * t);
    float o0 = a0f * inv + bv.x;
    float o1 = a1f * inv + bv.y;
    float o2 = a2f * inv + bv.z;
    float o3 = a3f * inv + bv.w;
    o0 = o0 > 0.f ? o0 : expm1f(o0);
    o1 = o1 > 0.f ? o1 : expm1f(o1);
    o2 = o2 > 0.f ? o2 : expm1f(o2);
    o3 = o3 > 0.f ? o3 : expm1f(o3);
    unsigned short rr[4] = { f2b(o0), f2b(o1), f2b(o2), f2b(o3) };
    *(uint2*)(hmid + (size_t)d * HC1 + 4 * t) = *(uint2*)rr;
}

// ================= layer 2: MFMA GEMM, BM=64 =================
// 4 waves. Wave w: rows [b*64 + w*16, +16) x 48 cols. A direct from global
// (streamed once); B (48x512) staged in LDS.
__global__ __launch_bounds__(256) void gemm2_mfma(
    const __hip_bfloat16* __restrict__ hmid, const __hip_bfloat16* __restrict__ W2T,
    const float* __restrict__ a_src2, const float* __restrict__ a_dst2,
    float* __restrict__ h2, float* __restrict__ e_src2, float* __restrict__ e_dst2,
    int N)
{
    __shared__ __hip_bfloat16 Bs[48][520];
    const int tid = threadIdx.x;

    {
        const short* wp = (const short*)W2T;
#pragma unroll
        for (int i = 0; i < 12; ++i) {
            int idx = tid + i * 256;
            int row = idx >> 6, ch = idx & 63;
            *(short8*)(&Bs[row][ch * 8]) = *(const short8*)(wp + (size_t)row * HC1 + ch * 8);
        }
    }
    __syncthreads();

    const int w = tid >> 6;
    const int lane = tid & 63;
    const int r = lane & 15, g = lane >> 4;
    const int rowW = blockIdx.x * 64 + w * 16;

    int arow = rowW + r; if (arow >= N) arow = N - 1;
    const short* ap = (const short*)hmid + (size_t)arow * HC1 + 8 * g;

    f32x4 acc[3] = {};
#pragma unroll 4
    for (int kk = 0; kk < HC1; kk += 32) {
        short8 af = *(const short8*)(ap + kk);
        short8 bf[3];
#pragma unroll
        for (int t = 0; t < 3; ++t)
            bf[t] = *(const short8*)(&Bs[t * 16 + r][kk + 8 * g]);
#pragma unroll
        for (int t = 0; t < 3; ++t)
            acc[t] = __builtin_amdgcn_mfma_f32_16x16x32_bf16(af, bf[t], acc[t], 0, 0, 0);
    }

    // ---- store h2 ----
#pragma unroll
    for (int t = 0; t < 3; ++t) {
        int c = t * 16 + r;
        if (c < OUT_DIM) {
#pragma unroll
            for (int q = 0; q < 4; ++q) {
                int row = rowW + 4 * g + q;
                if (row < N) h2[(size_t)row * OUT_DIM + c] = acc[t][q];
            }
        }
    }

    // ---- fused logits2 ----
    float as[3], ad[3];
#pragma unroll
    for (int t = 0; t < 3; ++t) {
        int c = t * 16 + r;
        as[t] = (c < OUT_DIM) ? a_src2[c] : 0.f;
        ad[t] = (c < OUT_DIM) ? a_dst2[c] : 0.f;
    }
    float ps[4] = {}, pd[4] = {};
#pragma unroll
    for (int t = 0; t < 3; ++t)
#pragma unroll
        for (int q = 0; q < 4; ++q) {
            ps[q] += acc[t][q] * as[t];
            pd[q] += acc[t][q] * ad[t];
        }
#pragma unroll
    for (int off = 1; off < 16; off <<= 1)
#pragma unroll
        for (int q = 0; q < 4; ++q) {
            ps[q] += __shfl_xor(ps[q], off);
            pd[q] += __shfl_xor(pd[q], off);
        }
    if (r == 0) {
#pragma unroll
        for (int q = 0; q < 4; ++q) {
            int row = rowW + 4 * g + q;
            if (row < N) { e_src2[row] = ps[q]; e_dst2[row] = pd[q]; }
        }
    }
}

// ================= gather layer 2 (inline softmax) =================
__global__ __launch_bounds__(256) void gather2_kernel(
    const int* __restrict__ rowptr, const int* __restrict__ csr_src,
    const float* __restrict__ h2, const float* __restrict__ e_src,
    const float* __restrict__ e_dst, const float* __restrict__ b2,
    float* __restrict__ out, int N)
{
    int wid = (blockIdx.x * blockDim.x + threadIdx.x) >> 6;
    if (wid >= N) return;
    int lane = threadIdx.x & 63;
    int base = rowptr[wid], end = rowptr[wid + 1];
    float ed = e_dst[wid];
    bool act = lane < OUT_DIM;
    int ln = act ? lane : 0;

    float acc = 0.f, ssum = 0.f;
    int j = base;
    for (; j + 4 <= end; j += 4) {
        int s0 = csr_src[j], s1 = csr_src[j + 1], s2 = csr_src[j + 2], s3 = csr_src[j + 3];
        float v0 = e_src[s0] + ed, v1 = e_src[s1] + ed;
        float v2 = e_src[s2] + ed, v3 = e_src[s3] + ed;
        float f0 = h2[(size_t)s0 * OUT_DIM + ln];
        float f1 = h2[(size_t)s1 * OUT_DIM + ln];
        float f2 = h2[(size_t)s2 * OUT_DIM + ln];
        float f3 = h2[(size_t)s3 * OUT_DIM + ln];
        float e0 = __expf(LRELU(v0)), e1 = __expf(LRELU(v1));
        float e2 = __expf(LRELU(v2)), e3 = __expf(LRELU(v3));
        acc += e0 * f0 + e1 * f1 + e2 * f2 + e3 * f3;
        ssum += e0 + e1 + e2 + e3;
    }
    for (; j < end; ++j) {
        int s0 = csr_src[j];
        float v0 = e_src[s0] + ed;
        float f0 = h2[(size_t)s0 * OUT_DIM + ln];
        float e0 = __expf(LRELU(v0));
        acc += e0 * f0;
        ssum += e0;
    }
    if (act)
        out[(size_t)wid * OUT_DIM + lane] = acc / ssum + b2[lane];
}

extern "C" void kernel_launch(void* const* d_in, const int* in_sizes, int n_in,
                              void* d_out, int out_size, void* d_ws, size_t ws_size,
                              hipStream_t stream)
{
    const float* x      = (const float*)d_in[0];
    const int*   ei     = (const int*)d_in[1];
    const float* W1     = (const float*)d_in[2];
    const float* a_src1 = (const float*)d_in[3];
    const float* a_dst1 = (const float*)d_in[4];
    const float* b1     = (const float*)d_in[5];
    const float* W2     = (const float*)d_in[6];
    const float* a_src2 = (const float*)d_in[7];
    const float* a_dst2 = (const float*)d_in[8];
    const float* b2     = (const float*)d_in[9];
    float* out = (float*)d_out;

    const int N  = in_sizes[0] / IN_DIM;   // 50000
    const int E  = in_sizes[1] / 2;        // 400000
    const int ET = E + N;                  // 450000

    char* p = (char*)d_ws;
    auto alloc = [&](size_t bytes) -> void* {
        void* r = (void*)p;
        p += (bytes + 255) & ~(size_t)255;
        return r;
    };
    __hip_bfloat16* h1b    = (__hip_bfloat16*)alloc((size_t)N * HC1 * 2);
    __hip_bfloat16* hmid   = (__hip_bfloat16*)alloc((size_t)N * HC1 * 2);
    float*    h2      = (float*)alloc((size_t)N * OUT_DIM * 4);
    float*    e_src1  = (float*)alloc((size_t)N * HEADS * 4);
    float*    e_dst1  = (float*)alloc((size_t)N * HEADS * 4);
    float*    e_src2  = (float*)alloc((size_t)N * 4);
    float*    e_dst2  = (float*)alloc((size_t)N * 4);
    int*      deg     = (int*)alloc((size_t)N * 4);
    int*      rowptr  = (int*)alloc((size_t)(N + 1) * 4);
    int*      cursor  = (int*)alloc((size_t)N * 4);
    int*      csr_src = (int*)alloc((size_t)ET * 4);
    int*      aux     = (int*)alloc(256 * 4);
    __hip_bfloat16* W1T = (__hip_bfloat16*)alloc((size_t)HC1 * IN_DIM * 2);
    __hip_bfloat16* W2T = (__hip_bfloat16*)alloc((size_t)48 * HC1 * 2);

    const int nbN  = (N + 255) / 256;
    const int nbET = (ET + 255) / 256;

    // ---- weight prep ----
    prep_w1t<<<(HC1 * IN_DIM + 255) / 256, 256, 0, stream>>>(W1, W1T);
    prep_w2t<<<(48 * HC1 + 255) / 256, 256, 0, stream>>>(W2, W2T);

    // ---- CSR build ----
    hipMemsetAsync(deg, 0, (size_t)N * 4, stream);
    degree_kernel<<<nbET, 256, 0, stream>>>(ei, deg, E, ET);
    scan1_kernel<<<nbN, 256, 0, stream>>>(deg, rowptr, aux, N);
    scan_aux_kernel<<<1, 256, 0, stream>>>(aux, nbN);
    scan_add_kernel<<<nbN, 256, 0, stream>>>(rowptr, aux, N, ET);
    hipMemcpyAsync(cursor, rowptr, (size_t)N * 4, hipMemcpyDeviceToDevice, stream);
    build_kernel<<<nbET, 256, 0, stream>>>(ei, cursor, csr_src, E, ET);

    // ---- layer 1 ----
    gemm1_mfma<<<(N + 63) / 64, 512, 0, stream>>>(x, W1T, a_src1, a_dst1, h1b,
                                                  e_src1, e_dst1, N);
    gather1_kernel<<<(N + 1) / 2, 256, 0, stream>>>(rowptr, csr_src, h1b, e_src1,
                                                    e_dst1, b1, hmid, N);

    // ---- layer 2 ----
    gemm2_mfma<<<(N + 63) / 64, 256, 0, stream>>>(hmid, W2T, a_src2, a_dst2, h2,
                                                  e_src2, e_dst2, N);
    gather2_kernel<<<(N + 3) / 4, 256, 0, stream>>>(rowptr, csr_src, h2, e_src2,
                                                    e_dst2, b2, out, N);
}